// Round 1
// baseline (1569.281 us; speedup 1.0000x reference)
//
#include <hip/hip_runtime.h>
#include <hip/hip_bf16.h>
#include <math.h>

#define NF 6
#define GG 8
#define NG 48          // NF*GG
#define QL 4096
#define DIMC 256
#define NHEAD 4
#define DHEAD 64
#define SCALE 0.125f
#define EPSLN 1e-5f

__device__ __forceinline__ unsigned short f2bf(float x) {
  union { float f; unsigned u; } v; v.f = x;
  unsigned r = v.u + 0x7FFFu + ((v.u >> 16) & 1u);
  return (unsigned short)(r >> 16);
}
__device__ __forceinline__ float bfbits_lo(unsigned pp) {
  union { unsigned u; float f; } v; v.u = pp << 16; return v.f;
}
__device__ __forceinline__ float bfbits_hi(unsigned pp) {
  union { unsigned u; float f; } v; v.u = pp & 0xFFFF0000u; return v.f;
}
__device__ __forceinline__ float bf2f(unsigned short s) {
  union { unsigned u; float f; } v; v.u = ((unsigned)s) << 16; return v.f;
}

// Stage 48 rows of k/v (contiguous 256-f32 rows), LayerNorm them, store bf16 to LDS.
// 4 threads per row (threads 0..191), each holds 64 elems in registers.
__device__ __forceinline__ void stage_ln_rows(
    const float* __restrict__ src, int qpos,
    const float* __restrict__ g, const float* __restrict__ b,
    unsigned short* s_ln, int t)
{
  if (t < NG * 4) {
    int r = t >> 2, sl = t & 3;
    int n = r >> 3, gg = r & 7;
    const float4* row = (const float4*)(src + ((size_t)(n * QL + qpos) * GG + gg) * DIMC);
    float4 dat[16];
    float s = 0.f, s2 = 0.f;
#pragma unroll
    for (int kk = 0; kk < 16; ++kk) {
      float4 x = row[sl + 4 * kk];
      dat[kk] = x;
      s  += x.x + x.y + x.z + x.w;
      s2 += x.x * x.x + x.y * x.y + x.z * x.z + x.w * x.w;
    }
    s  += __shfl_xor(s, 1, 64);  s  += __shfl_xor(s, 2, 64);
    s2 += __shfl_xor(s2, 1, 64); s2 += __shfl_xor(s2, 2, 64);
    float mu  = s * (1.f / 256.f);
    float var = s2 * (1.f / 256.f) - mu * mu;
    float istd = rsqrtf(var + EPSLN);
    const float4* g4 = (const float4*)g;
    const float4* b4 = (const float4*)b;
#pragma unroll
    for (int kk = 0; kk < 16; ++kk) {
      int c = sl + 4 * kk;
      int d = 4 * c;
      float4 gv = g4[c], bv = b4[c], x = dat[kk];
      unsigned short o0 = f2bf((x.x - mu) * istd * gv.x + bv.x);
      unsigned short o1 = f2bf((x.y - mu) * istd * gv.y + bv.y);
      unsigned short o2 = f2bf((x.z - mu) * istd * gv.z + bv.z);
      unsigned short o3 = f2bf((x.w - mu) * istd * gv.w + bv.w);
      unsigned* dst = (unsigned*)(s_ln + r * 256 + d);
      dst[0] = (unsigned)o0 | ((unsigned)o1 << 16);
      dst[1] = (unsigned)o2 | ((unsigned)o3 << 16);
    }
  }
}

// [48x256](bf16 LDS) @ [256x256](f32 global) + bias -> bf16 LDS (stride 258)
__device__ __forceinline__ void gemm48(
    const unsigned short* s_ln, const float* __restrict__ W,
    const float* __restrict__ bias, unsigned short* s_out, int t)
{
  int ty = t >> 6, tx = t & 63;
  int r0 = ty * 12;
  int j = tx * 4;
  float acc[12][4];
#pragma unroll
  for (int r = 0; r < 12; ++r)
    acc[r][0] = acc[r][1] = acc[r][2] = acc[r][3] = 0.f;
  const float4* W4 = (const float4*)W;
  for (int d = 0; d < DIMC; d += 2) {
    float4 wA = W4[d * 64 + tx];
    float4 wB = W4[(d + 1) * 64 + tx];
#pragma unroll
    for (int r = 0; r < 12; ++r) {
      unsigned pp = *(const unsigned*)(s_ln + (r0 + r) * 256 + d);
      float x0 = bfbits_lo(pp), x1 = bfbits_hi(pp);
      acc[r][0] += x0 * wA.x; acc[r][1] += x0 * wA.y;
      acc[r][2] += x0 * wA.z; acc[r][3] += x0 * wA.w;
      acc[r][0] += x1 * wB.x; acc[r][1] += x1 * wB.y;
      acc[r][2] += x1 * wB.z; acc[r][3] += x1 * wB.w;
    }
  }
  float4 bb = ((const float4*)bias)[tx];
#pragma unroll
  for (int r = 0; r < 12; ++r) {
    unsigned* dst = (unsigned*)(s_out + (r0 + r) * 258 + j);
    dst[0] = (unsigned)f2bf(acc[r][0] + bb.x) | ((unsigned)f2bf(acc[r][1] + bb.y) << 16);
    dst[1] = (unsigned)f2bf(acc[r][2] + bb.z) | ((unsigned)f2bf(acc[r][3] + bb.w) << 16);
  }
}

// One block per query pixel: LN+project q/k/v, scores, softmax, PV -> aws[qpos][256]
__global__ void __launch_bounds__(256)
attn_kernel(const float* __restrict__ q, const float* __restrict__ k,
            const float* __restrict__ v, const int* __restrict__ mask,
            const float* __restrict__ lnqg, const float* __restrict__ lnqb,
            const float* __restrict__ wq, const float* __restrict__ bq,
            const float* __restrict__ lnkg, const float* __restrict__ lnkb,
            const float* __restrict__ wk, const float* __restrict__ bk,
            const float* __restrict__ lnvg, const float* __restrict__ lnvb,
            const float* __restrict__ wv, const float* __restrict__ bv,
            float* __restrict__ aws)
{
  const int qpos = blockIdx.x;
  const int t = threadIdx.x;

  __shared__ __align__(16) unsigned char smem[59456];
  unsigned short* s_ln  = (unsigned short*)smem;                      // 48*256 bf16
  unsigned short* s_pro = (unsigned short*)(smem + 24576);            // 48*258 bf16 (kh then vh)
  float*          s_qraw = (float*)(smem + 24576);                    // alias: 6*256 f32
  unsigned short* s_lnq = (unsigned short*)(smem + 49344);            // 6*256 bf16
  float*          qh    = (float*)(smem + 52416);                     // 6*260 f32 (scaled)
  float*          att   = (float*)(smem + 58656);                     // 192 f32
  int*            maskv = (int*)(smem + 59424);                       // 6

  // ---- P0: stage q rows (strided gather) + LN ----
  for (int i = t; i < NF * DIMC; i += 256) {
    int n = i >> 8, d = i & 255;
    s_qraw[i] = q[(size_t)(n * DIMC + d) * QL + qpos];
  }
  if (t < NF) maskv[t] = mask[t * QL + qpos];
  __syncthreads();
  {
    int r = t >> 5, l = t & 31;
    if (r < NF) {
      float s = 0.f, s2 = 0.f;
#pragma unroll
      for (int kk = 0; kk < 8; ++kk) {
        float x = s_qraw[r * 256 + l + 32 * kk];
        s += x; s2 += x * x;
      }
#pragma unroll
      for (int m = 16; m >= 1; m >>= 1) {
        s += __shfl_xor(s, m, 64); s2 += __shfl_xor(s2, m, 64);
      }
      float mu = s * (1.f / 256.f);
      float var = s2 * (1.f / 256.f) - mu * mu;
      float istd = rsqrtf(var + EPSLN);
#pragma unroll
      for (int kk = 0; kk < 8; ++kk) {
        int d = l + 32 * kk;
        float x = s_qraw[r * 256 + d];
        s_lnq[r * 256 + d] = f2bf((x - mu) * istd * lnqg[d] + lnqb[d]);
      }
    }
  }
  __syncthreads();

  // ---- P1: qh = SCALE*(LN(q) @ wq + bq), thread = output column ----
  {
    float acc[NF] = {0.f, 0.f, 0.f, 0.f, 0.f, 0.f};
    int j = t;
    for (int d = 0; d < DIMC; d += 2) {
      float wA = wq[d * DIMC + j];
      float wB = wq[(d + 1) * DIMC + j];
#pragma unroll
      for (int r = 0; r < NF; ++r) {
        unsigned pp = *(const unsigned*)(s_lnq + r * 256 + d);
        acc[r] += bfbits_lo(pp) * wA + bfbits_hi(pp) * wB;
      }
    }
    float bb = bq[j];
#pragma unroll
    for (int r = 0; r < NF; ++r) qh[r * 260 + j] = SCALE * (acc[r] + bb);
  }
  __syncthreads();   // also: s_qraw (alias of s_pro) now dead

  // ---- P2/P3: K path ----
  stage_ln_rows(k, qpos, lnkg, lnkb, s_ln, t);
  __syncthreads();
  gemm48(s_ln, wk, bk, s_pro, t);
  __syncthreads();

  // ---- P4: scores (t<192): m = t/48, key = t%48 ----
  if (t < NHEAD * NG) {
    int m = t / NG, kkk = t % NG;
    int n = kkk >> 3;
    const float* qrow = qh + n * 260 + m * DHEAD;
    const unsigned short* krow = s_pro + kkk * 258 + m * DHEAD;
    float dot = 0.f;
#pragma unroll
    for (int dd = 0; dd < DHEAD; dd += 2) {
      unsigned pp = *(const unsigned*)(krow + dd);
      dot += qrow[dd] * bfbits_lo(pp) + qrow[dd + 1] * bfbits_hi(pp);
    }
    att[t] = maskv[n] ? dot : -1e9f;
  }
  __syncthreads();

  // ---- P5: softmax over 48, one thread per head ----
  if (t < NHEAD) {
    float mx = -3.0e38f;
    for (int i = 0; i < NG; ++i) mx = fmaxf(mx, att[t * NG + i]);
    float sm = 0.f;
    for (int i = 0; i < NG; ++i) {
      float e = expf(att[t * NG + i] - mx);
      att[t * NG + i] = e; sm += e;
    }
    float inv = 1.f / sm;
    for (int i = 0; i < NG; ++i) att[t * NG + i] *= inv;
  }
  __syncthreads();

  // ---- P6/P7: V path (reuse buffers) ----
  stage_ln_rows(v, qpos, lnvg, lnvb, s_ln, t);
  __syncthreads();
  gemm48(s_ln, wv, bv, s_pro, t);
  __syncthreads();

  // ---- P8: a[col=t] = sum_k att[m][k] * vh[k][col]  (col = m*64+dh = t) ----
  {
    int m = t >> 6;
    float acc = 0.f;
#pragma unroll
    for (int kkk = 0; kkk < NG; ++kkk)
      acc += att[m * NG + kkk] * bf2f(s_pro[kkk * 258 + t]);
    aws[(size_t)qpos * DIMC + t] = acc;
  }
}

__device__ __forceinline__ void ln_rows8(float* buf, int stride,
    const float* __restrict__ g, const float* __restrict__ b, int t)
{
  int r = t >> 5, l = t & 31;
  float s = 0.f, s2 = 0.f;
#pragma unroll
  for (int kk = 0; kk < 8; ++kk) {
    float x = buf[r * stride + l + 32 * kk];
    s += x; s2 += x * x;
  }
#pragma unroll
  for (int m = 16; m >= 1; m >>= 1) {
    s += __shfl_xor(s, m, 64); s2 += __shfl_xor(s2, m, 64);
  }
  float mu = s * (1.f / 256.f);
  float var = s2 * (1.f / 256.f) - mu * mu;
  float istd = rsqrtf(var + EPSLN);
#pragma unroll
  for (int kk = 0; kk < 8; ++kk) {
    int d = l + 32 * kk;
    buf[r * stride + d] = (buf[r * stride + d] - mu) * istd * g[d] + b[d];
  }
}

// 8 rows per block: z = a@wp+bp+skip; LN; h = gelu(z@w1+b1); t2 = h@w2+b2; LN(z+t2); transpose store.
__global__ void __launch_bounds__(256)
epi_kernel(const float* __restrict__ aws, const float* __restrict__ skip,
           const float* __restrict__ wp, const float* __restrict__ bp,
           const float* __restrict__ lng1, const float* __restrict__ lnb1,
           const float* __restrict__ w1, const float* __restrict__ b1,
           const float* __restrict__ w2, const float* __restrict__ b2,
           const float* __restrict__ lng2, const float* __restrict__ lnb2,
           float* __restrict__ out)
{
  const int t = threadIdx.x;
  const int q0 = blockIdx.x * 8;
  __shared__ float s_a[8 * 256];
  __shared__ float s_z[8 * 260];
  __shared__ float s_h[8 * 516];

#pragma unroll
  for (int r = 0; r < 8; ++r)
    s_a[r * 256 + t] = aws[(size_t)(q0 + r) * 256 + t];
  __syncthreads();

  const int ty = t >> 6, tx = t & 63;
  const int r0 = ty * 2;
  const int j = tx * 4;

  // z = a @ wp + bp + skip
  {
    float acc[2][4] = {{0.f,0.f,0.f,0.f},{0.f,0.f,0.f,0.f}};
    const float4* W4 = (const float4*)wp;
    for (int d = 0; d < 256; ++d) {
      float4 w = W4[d * 64 + tx];
      float x0 = s_a[r0 * 256 + d];
      float x1 = s_a[(r0 + 1) * 256 + d];
      acc[0][0] += x0 * w.x; acc[0][1] += x0 * w.y; acc[0][2] += x0 * w.z; acc[0][3] += x0 * w.w;
      acc[1][0] += x1 * w.x; acc[1][1] += x1 * w.y; acc[1][2] += x1 * w.z; acc[1][3] += x1 * w.w;
    }
    float4 bb = ((const float4*)bp)[tx];
#pragma unroll
    for (int rr = 0; rr < 2; ++rr) {
      int r = r0 + rr;
      s_z[r * 260 + j + 0] = acc[rr][0] + bb.x + skip[(size_t)(j + 0) * QL + q0 + r];
      s_z[r * 260 + j + 1] = acc[rr][1] + bb.y + skip[(size_t)(j + 1) * QL + q0 + r];
      s_z[r * 260 + j + 2] = acc[rr][2] + bb.z + skip[(size_t)(j + 2) * QL + q0 + r];
      s_z[r * 260 + j + 3] = acc[rr][3] + bb.w + skip[(size_t)(j + 3) * QL + q0 + r];
    }
  }
  __syncthreads();

  ln_rows8(s_z, 260, lng1, lnb1, t);
  __syncthreads();

  // h = gelu(z @ w1 + b1), 512 cols
  {
    float acc[2][8] = {{0,0,0,0,0,0,0,0},{0,0,0,0,0,0,0,0}};
    const float4* W4 = (const float4*)w1;   // 256 x 512
    for (int d = 0; d < 256; ++d) {
      float4 wa = W4[d * 128 + tx];
      float4 wb = W4[d * 128 + 64 + tx];
      float x0 = s_z[r0 * 260 + d];
      float x1 = s_z[(r0 + 1) * 260 + d];
      acc[0][0] += x0 * wa.x; acc[0][1] += x0 * wa.y; acc[0][2] += x0 * wa.z; acc[0][3] += x0 * wa.w;
      acc[0][4] += x0 * wb.x; acc[0][5] += x0 * wb.y; acc[0][6] += x0 * wb.z; acc[0][7] += x0 * wb.w;
      acc[1][0] += x1 * wa.x; acc[1][1] += x1 * wa.y; acc[1][2] += x1 * wa.z; acc[1][3] += x1 * wa.w;
      acc[1][4] += x1 * wb.x; acc[1][5] += x1 * wb.y; acc[1][6] += x1 * wb.z; acc[1][7] += x1 * wb.w;
    }
#pragma unroll
    for (int rr = 0; rr < 2; ++rr) {
      int r = r0 + rr;
#pragma unroll
      for (int p = 0; p < 2; ++p) {
#pragma unroll
        for (int c = 0; c < 4; ++c) {
          int jj = 4 * tx + 256 * p + c;
          float val = acc[rr][p * 4 + c] + b1[jj];
          s_h[r * 516 + jj] = 0.5f * val * (1.f + erff(val * 0.70710678118654752f));
        }
      }
    }
  }
  __syncthreads();

  // t2 = h @ w2 + b2 ; s_a = z + t2   (reuse s_a)
  {
    float acc[2][4] = {{0.f,0.f,0.f,0.f},{0.f,0.f,0.f,0.f}};
    const float4* W4 = (const float4*)w2;   // 512 x 256
    for (int d = 0; d < 512; ++d) {
      float4 w = W4[d * 64 + tx];
      float x0 = s_h[r0 * 516 + d];
      float x1 = s_h[(r0 + 1) * 516 + d];
      acc[0][0] += x0 * w.x; acc[0][1] += x0 * w.y; acc[0][2] += x0 * w.z; acc[0][3] += x0 * w.w;
      acc[1][0] += x1 * w.x; acc[1][1] += x1 * w.y; acc[1][2] += x1 * w.z; acc[1][3] += x1 * w.w;
    }
    float4 bb = ((const float4*)b2)[tx];
#pragma unroll
    for (int rr = 0; rr < 2; ++rr) {
      int r = r0 + rr;
      s_a[r * 256 + j + 0] = s_z[r * 260 + j + 0] + acc[rr][0] + bb.x;
      s_a[r * 256 + j + 1] = s_z[r * 260 + j + 1] + acc[rr][1] + bb.y;
      s_a[r * 256 + j + 2] = s_z[r * 260 + j + 2] + acc[rr][2] + bb.z;
      s_a[r * 256 + j + 3] = s_z[r * 260 + j + 3] + acc[rr][3] + bb.w;
    }
  }
  __syncthreads();

  // final LN + transposed store
  {
    int r = t >> 5, l = t & 31;
    float s = 0.f, s2 = 0.f;
#pragma unroll
    for (int kk = 0; kk < 8; ++kk) {
      float x = s_a[r * 256 + l + 32 * kk];
      s += x; s2 += x * x;
    }
#pragma unroll
    for (int m = 16; m >= 1; m >>= 1) {
      s += __shfl_xor(s, m, 64); s2 += __shfl_xor(s2, m, 64);
    }
    float mu = s * (1.f / 256.f);
    float var = s2 * (1.f / 256.f) - mu * mu;
    float istd = rsqrtf(var + EPSLN);
#pragma unroll
    for (int kk = 0; kk < 8; ++kk) {
      int d = l + 32 * kk;
      float val = (s_a[r * 256 + d] - mu) * istd * lng2[d] + lnb2[d];
      out[(size_t)d * QL + q0 + r] = val;
    }
  }
}

extern "C" void kernel_launch(void* const* d_in, const int* in_sizes, int n_in,
                              void* d_out, int out_size, void* d_ws, size_t ws_size,
                              hipStream_t stream) {
  (void)in_sizes; (void)n_in; (void)out_size; (void)ws_size;
  const float* q     = (const float*)d_in[0];
  const float* k     = (const float*)d_in[1];
  const float* v     = (const float*)d_in[2];
  const float* skip  = (const float*)d_in[3];
  const int*   mask  = (const int*)d_in[4];
  const float* lnqg  = (const float*)d_in[5];
  const float* lnqb  = (const float*)d_in[6];
  const float* wq    = (const float*)d_in[7];
  const float* bq    = (const float*)d_in[8];
  const float* lnkg  = (const float*)d_in[9];
  const float* lnkb  = (const float*)d_in[10];
  const float* wk    = (const float*)d_in[11];
  const float* bk    = (const float*)d_in[12];
  const float* lnvg  = (const float*)d_in[13];
  const float* lnvb  = (const float*)d_in[14];
  const float* wv    = (const float*)d_in[15];
  const float* bv    = (const float*)d_in[16];
  const float* wp    = (const float*)d_in[17];
  const float* bp    = (const float*)d_in[18];
  const float* lng1  = (const float*)d_in[19];
  const float* lnb1  = (const float*)d_in[20];
  const float* w1    = (const float*)d_in[21];
  const float* b1    = (const float*)d_in[22];
  const float* w2    = (const float*)d_in[23];
  const float* b2    = (const float*)d_in[24];
  const float* lng2  = (const float*)d_in[25];
  const float* lnb2  = (const float*)d_in[26];
  float* out = (float*)d_out;
  float* aws = (float*)d_ws;   // 4096*256 f32 = 4 MB

  hipLaunchKernelGGL(attn_kernel, dim3(QL), dim3(256), 0, stream,
                     q, k, v, mask, lnqg, lnqb, wq, bq,
                     lnkg, lnkb, wk, bk, lnvg, lnvb, wv, bv, aws);
  hipLaunchKernelGGL(epi_kernel, dim3(QL / 8), dim3(256), 0, stream,
                     aws, skip, wp, bp, lng1, lnb1, w1, b1, w2, b2, lng2, lnb2, out);
}

// Round 2
// 807.095 us; speedup vs baseline: 1.9444x; 1.9444x over previous
//
#include <hip/hip_runtime.h>
#include <hip/hip_bf16.h>
#include <math.h>

#define NF 6
#define GG 8
#define NG 48
#define QL 4096
#define DIMC 256
#define NHEAD 4
#define DHEAD 64
#define SCALE 0.125f
#define EPSLN 1e-5f

#define LDPAD 264   // bf16 elements per LDS row (256 + 8): 2-way-max bank aliasing for b128 frag reads

typedef __bf16 bf16x8 __attribute__((ext_vector_type(8)));
typedef float  f32x4  __attribute__((ext_vector_type(4)));

// ws layout (bytes)
#define OFF_WQT 0u
#define OFF_WKT 131072u
#define OFF_WVT 262144u
#define OFF_QH  393216u
#define OFF_PBUF 12976128u     // kh, later overwritten by vh (196608 rows x 256 bf16)
#define OFF_ATT 113639424u     // 4096 x 192 f32
#define OFF_AWS 116785152u     // 4096 x 256 f32

__device__ __forceinline__ unsigned short f2bf(float x) {
  union { float f; unsigned u; } v; v.f = x;
  unsigned r = v.u + 0x7FFFu + ((v.u >> 16) & 1u);
  return (unsigned short)(r >> 16);
}
__device__ __forceinline__ float bf2f(unsigned short s) {
  union { unsigned u; float f; } v; v.u = ((unsigned)s) << 16; return v.f;
}

// ---------------- K0: W[256x256] f32 -> W^T[256x256] bf16 ----------------
__global__ void __launch_bounds__(256)
prep_kernel(const float* __restrict__ wq, const float* __restrict__ wk,
            const float* __restrict__ wv, unsigned short* __restrict__ ws_u16)
{
  __shared__ unsigned short s_t[128 * LDPAD];
  const int t = threadIdx.x;
  const int mat = blockIdx.x >> 1;
  const int j0 = (blockIdx.x & 1) * 128;
  const float* src = (mat == 0) ? wq : (mat == 1) ? wk : wv;
  unsigned short* dst = ws_u16 + ((mat == 0) ? (OFF_WQT/2) : (mat == 1) ? (OFF_WKT/2) : (OFF_WVT/2));

  const int jj = t & 127;
  const int dh = t >> 7;
  for (int it = 0; it < 128; ++it) {
    int d = it * 2 + dh;
    float val = src[d * 256 + j0 + jj];
    s_t[jj * LDPAD + d] = f2bf(val);
  }
  __syncthreads();
  unsigned char* db = (unsigned char*)(dst + j0 * 256);
#pragma unroll
  for (int i = 0; i < 16; ++i) {
    int lin = i * 4096 + t * 16;
    int r = lin >> 9, off = lin & 511;
    uint4 v = *(const uint4*)((const unsigned char*)s_t + r * (LDPAD * 2) + off);
    *(uint4*)(db + lin) = v;
  }
}

// ---------------- K1: LN + [128 x 256] @ W -> bf16 out, MFMA ----------------
// qmode==0: src rows contiguous (k/v). qmode==1: src is q (n, d, qpos), gather-transpose.
__global__ void __launch_bounds__(256, 2)
proj_kernel(const float* __restrict__ src,
            const float* __restrict__ lng, const float* __restrict__ lnb,
            const unsigned short* __restrict__ wT,
            const float* __restrict__ bias,
            unsigned short* __restrict__ outp,
            int qmode)
{
  __shared__ __align__(16) unsigned short s_x[128 * LDPAD];
  __shared__ float s_bias[256];
  const int t = threadIdx.x;
  const int blk = blockIdx.x;

  s_bias[t] = bias[t];

  if (!qmode) {
    const int row = t >> 1, half = t & 1;
    const float4* rp = (const float4*)(src + ((size_t)(blk * 128 + row)) * 256 + half * 128);
    float4 dat[32];
    float s = 0.f, s2 = 0.f;
#pragma unroll
    for (int i = 0; i < 32; ++i) {
      float4 x = rp[i]; dat[i] = x;
      s  += x.x + x.y + x.z + x.w;
      s2 += x.x * x.x + x.y * x.y + x.z * x.z + x.w * x.w;
    }
    s  += __shfl_xor(s, 1, 64);
    s2 += __shfl_xor(s2, 1, 64);
    float mu  = s * (1.f / 256.f);
    float var = s2 * (1.f / 256.f) - mu * mu;
    float istd = rsqrtf(var + EPSLN);
#pragma unroll
    for (int i = 0; i < 32; ++i) {
      float4 g  = *(const float4*)(lng + half * 128 + i * 4);
      float4 bb = *(const float4*)(lnb + half * 128 + i * 4);
      float4 x = dat[i];
      unsigned d0 = (unsigned)f2bf((x.x - mu) * istd * g.x + bb.x) |
                    ((unsigned)f2bf((x.y - mu) * istd * g.y + bb.y) << 16);
      unsigned d1 = (unsigned)f2bf((x.z - mu) * istd * g.z + bb.z) |
                    ((unsigned)f2bf((x.w - mu) * istd * g.w + bb.w) << 16);
      unsigned long long dd = (unsigned long long)d0 | ((unsigned long long)d1 << 32);
      *(unsigned long long*)(s_x + row * LDPAD + half * 128 + i * 4) = dd;
    }
  } else {
    const int n = blk >> 5, qp0 = (blk & 31) << 7;
    const int l32 = t & 31;
    // phase A: transpose-stage raw bf16 (rows = qpos-local, cols = d)
    for (int it = 0; it < 32; ++it) {
      int dcol = it * 8 + (t >> 5);
      float4 x = *(const float4*)(src + ((size_t)(n * 256 + dcol)) * 4096 + qp0 + l32 * 4);
      s_x[(l32 * 4 + 0) * LDPAD + dcol] = f2bf(x.x);
      s_x[(l32 * 4 + 1) * LDPAD + dcol] = f2bf(x.y);
      s_x[(l32 * 4 + 2) * LDPAD + dcol] = f2bf(x.z);
      s_x[(l32 * 4 + 3) * LDPAD + dcol] = f2bf(x.w);
    }
    __syncthreads();
    // phase B: in-place LN per row
    const int row = t >> 1, half = t & 1;
    bf16x8 rv[16];
    float s = 0.f, s2 = 0.f;
#pragma unroll
    for (int i = 0; i < 16; ++i) {
      rv[i] = *(const bf16x8*)(s_x + row * LDPAD + half * 128 + i * 8);
#pragma unroll
      for (int j = 0; j < 8; ++j) { float xf = (float)rv[i][j]; s += xf; s2 += xf * xf; }
    }
    s  += __shfl_xor(s, 1, 64);
    s2 += __shfl_xor(s2, 1, 64);
    float mu  = s * (1.f / 256.f);
    float var = s2 * (1.f / 256.f) - mu * mu;
    float istd = rsqrtf(var + EPSLN);
#pragma unroll
    for (int i = 0; i < 16; ++i) {
      float4 ga = *(const float4*)(lng + half * 128 + i * 8);
      float4 gb = *(const float4*)(lng + half * 128 + i * 8 + 4);
      float4 ba = *(const float4*)(lnb + half * 128 + i * 8);
      float4 bb = *(const float4*)(lnb + half * 128 + i * 8 + 4);
      float gs[8] = {ga.x, ga.y, ga.z, ga.w, gb.x, gb.y, gb.z, gb.w};
      float bs[8] = {ba.x, ba.y, ba.z, ba.w, bb.x, bb.y, bb.z, bb.w};
      unsigned dw[4];
#pragma unroll
      for (int j = 0; j < 4; ++j) {
        unsigned short lo = f2bf(((float)rv[i][2 * j]     - mu) * istd * gs[2 * j]     + bs[2 * j]);
        unsigned short hi = f2bf(((float)rv[i][2 * j + 1] - mu) * istd * gs[2 * j + 1] + bs[2 * j + 1]);
        dw[j] = (unsigned)lo | ((unsigned)hi << 16);
      }
      uint4 u4 = make_uint4(dw[0], dw[1], dw[2], dw[3]);
      *(uint4*)(s_x + row * LDPAD + half * 128 + i * 8) = u4;
    }
  }
  __syncthreads();

  // MFMA: swapped operands (A = W^T frag, B = X frag) -> lane holds 4 consecutive out-cols
  const int wv_ = t >> 6, lane = t & 63;
  const int nhalf = wv_ & 1, mhalf = wv_ >> 1;
  const int lr = lane & 15, quad = lane >> 4;
  f32x4 acc[8][4];
  {
    f32x4 z = {0.f, 0.f, 0.f, 0.f};
#pragma unroll
    for (int a = 0; a < 8; ++a)
#pragma unroll
      for (int b = 0; b < 4; ++b) acc[a][b] = z;
  }
  for (int kt = 0; kt < 8; ++kt) {
    bf16x8 xf[4], wf[8];
#pragma unroll
    for (int mt = 0; mt < 4; ++mt)
      xf[mt] = *(const bf16x8*)(s_x + (mhalf * 64 + mt * 16 + lr) * LDPAD + kt * 32 + quad * 8);
#pragma unroll
    for (int nt = 0; nt < 8; ++nt)
      wf[nt] = *(const bf16x8*)(wT + ((nhalf * 128 + nt * 16 + lr) * 256 + kt * 32 + quad * 8));
#pragma unroll
    for (int nt = 0; nt < 8; ++nt)
#pragma unroll
      for (int mt = 0; mt < 4; ++mt)
        acc[nt][mt] = __builtin_amdgcn_mfma_f32_16x16x32_bf16(wf[nt], xf[mt], acc[nt][mt], 0, 0, 0);
  }
  __syncthreads();   // s_x dead -> reuse as out-stage

#pragma unroll
  for (int nt = 0; nt < 8; ++nt) {
    int n0 = nhalf * 128 + nt * 16 + quad * 4;
    float4 bb = *(const float4*)(s_bias + n0);
#pragma unroll
    for (int mt = 0; mt < 4; ++mt) {
      int m = mhalf * 64 + mt * 16 + lr;
      f32x4 a = acc[nt][mt];
      unsigned d0 = (unsigned)f2bf(a[0] + bb.x) | ((unsigned)f2bf(a[1] + bb.y) << 16);
      unsigned d1 = (unsigned)f2bf(a[2] + bb.z) | ((unsigned)f2bf(a[3] + bb.w) << 16);
      unsigned long long dd = (unsigned long long)d0 | ((unsigned long long)d1 << 32);
      *(unsigned long long*)(s_x + m * LDPAD + n0) = dd;
    }
  }
  __syncthreads();

  unsigned char* ob = (unsigned char*)outp + (size_t)blk * 65536;
#pragma unroll
  for (int i = 0; i < 16; ++i) {
    int lin = i * 4096 + t * 16;
    int r = lin >> 9, off = lin & 511;
    uint4 v = *(const uint4*)((const unsigned char*)s_x + r * (LDPAD * 2) + off);
    *(uint4*)(ob + lin) = v;
  }
}

// ---------------- K2: per-pixel scores + softmax -> att ----------------
__global__ void __launch_bounds__(256)
score_kernel(const unsigned short* __restrict__ qh, const unsigned short* __restrict__ kh,
             const int* __restrict__ mask, float* __restrict__ attg)
{
  const int p = blockIdx.x, t = threadIdx.x;
  __shared__ __align__(16) unsigned short s_k[NG * LDPAD];
  __shared__ __align__(16) unsigned short s_q[NF * LDPAD];
  __shared__ float s_att[NHEAD * NG];
  __shared__ int maskv[NF];

  // stage kh: 48 rows x 512B
#pragma unroll
  for (int i = 0; i < 6; ++i) {
    int cid = i * 256 + t;
    int key = cid >> 5, c16 = cid & 31;
    int n = key >> 3, kk = key & 7;
    const unsigned char* gp = (const unsigned char*)kh +
        (((size_t)n * QL + p) * 8 + kk) * 512 + c16 * 16;
    uint4 v = *(const uint4*)gp;
    *(uint4*)((unsigned char*)s_k + key * (LDPAD * 2) + c16 * 16) = v;
  }
  if (t < 192) {
    int row = t >> 5, c16 = t & 31;
    const unsigned char* gp = (const unsigned char*)qh + ((size_t)row * QL + p) * 512 + c16 * 16;
    uint4 v = *(const uint4*)gp;
    *(uint4*)((unsigned char*)s_q + row * (LDPAD * 2) + c16 * 16) = v;
  }
  if (t < NF) maskv[t] = mask[t * QL + p];
  __syncthreads();

  if (t < NHEAD * NG) {
    int m = t / NG, key = t % NG;
    int n = key >> 3;
    const __bf16* kr = (const __bf16*)(s_k + key * LDPAD + m * 64);
    const __bf16* qr = (const __bf16*)(s_q + n * LDPAD + m * 64);
    float dot = 0.f;
#pragma unroll
    for (int i = 0; i < 8; ++i) {
      bf16x8 kv = *(const bf16x8*)(kr + i * 8);
      bf16x8 qv = *(const bf16x8*)(qr + i * 8);
#pragma unroll
      for (int j = 0; j < 8; ++j) dot += (float)kv[j] * (float)qv[j];
    }
    s_att[t] = maskv[n] ? dot * SCALE : -1e9f;
  }
  __syncthreads();

  if (t < NHEAD) {
    float mx = -3.0e38f;
    for (int i = 0; i < NG; ++i) mx = fmaxf(mx, s_att[t * NG + i]);
    float sm = 0.f;
    for (int i = 0; i < NG; ++i) { float e = expf(s_att[t * NG + i] - mx); s_att[t * NG + i] = e; sm += e; }
    float inv = 1.f / sm;
    for (int i = 0; i < NG; ++i) s_att[t * NG + i] *= inv;
  }
  __syncthreads();

  if (t < NHEAD * NG) attg[(size_t)p * 192 + t] = s_att[t];
}

// ---------------- K3: per-pixel PV -> aws (f32) ----------------
__global__ void __launch_bounds__(256)
pv_kernel(const unsigned short* __restrict__ vh, const float* __restrict__ attg,
          float* __restrict__ aws)
{
  const int p = blockIdx.x, t = threadIdx.x;
  __shared__ __align__(16) unsigned short s_v[NG * LDPAD];
  __shared__ float s_att[NHEAD * NG];

#pragma unroll
  for (int i = 0; i < 6; ++i) {
    int cid = i * 256 + t;
    int key = cid >> 5, c16 = cid & 31;
    int n = key >> 3, kk = key & 7;
    const unsigned char* gp = (const unsigned char*)vh +
        (((size_t)n * QL + p) * 8 + kk) * 512 + c16 * 16;
    uint4 v = *(const uint4*)gp;
    *(uint4*)((unsigned char*)s_v + key * (LDPAD * 2) + c16 * 16) = v;
  }
  if (t < 192) s_att[t] = attg[(size_t)p * 192 + t];
  __syncthreads();

  const int m = t >> 6;
  float acc = 0.f;
#pragma unroll
  for (int key = 0; key < NG; ++key)
    acc += s_att[m * NG + key] * bf2f(s_v[key * LDPAD + t]);
  aws[(size_t)p * DIMC + t] = acc;
}

// ---------------- epilogue (unchanged from round 1) ----------------
__device__ __forceinline__ void ln_rows8(float* buf, int stride,
    const float* __restrict__ g, const float* __restrict__ b, int t)
{
  int r = t >> 5, l = t & 31;
  float s = 0.f, s2 = 0.f;
#pragma unroll
  for (int kk = 0; kk < 8; ++kk) {
    float x = buf[r * stride + l + 32 * kk];
    s += x; s2 += x * x;
  }
#pragma unroll
  for (int m = 16; m >= 1; m >>= 1) {
    s += __shfl_xor(s, m, 64); s2 += __shfl_xor(s2, m, 64);
  }
  float mu = s * (1.f / 256.f);
  float var = s2 * (1.f / 256.f) - mu * mu;
  float istd = rsqrtf(var + EPSLN);
#pragma unroll
  for (int kk = 0; kk < 8; ++kk) {
    int d = l + 32 * kk;
    buf[r * stride + d] = (buf[r * stride + d] - mu) * istd * g[d] + b[d];
  }
}

__global__ void __launch_bounds__(256)
epi_kernel(const float* __restrict__ aws, const float* __restrict__ skip,
           const float* __restrict__ wp, const float* __restrict__ bp,
           const float* __restrict__ lng1, const float* __restrict__ lnb1,
           const float* __restrict__ w1, const float* __restrict__ b1,
           const float* __restrict__ w2, const float* __restrict__ b2,
           const float* __restrict__ lng2, const float* __restrict__ lnb2,
           float* __restrict__ out)
{
  const int t = threadIdx.x;
  const int q0 = blockIdx.x * 8;
  __shared__ float s_a[8 * 256];
  __shared__ float s_z[8 * 260];
  __shared__ float s_h[8 * 516];

#pragma unroll
  for (int r = 0; r < 8; ++r)
    s_a[r * 256 + t] = aws[(size_t)(q0 + r) * 256 + t];
  __syncthreads();

  const int ty = t >> 6, tx = t & 63;
  const int r0 = ty * 2;
  const int j = tx * 4;

  {
    float acc[2][4] = {{0.f,0.f,0.f,0.f},{0.f,0.f,0.f,0.f}};
    const float4* W4 = (const float4*)wp;
    for (int d = 0; d < 256; ++d) {
      float4 w = W4[d * 64 + tx];
      float x0 = s_a[r0 * 256 + d];
      float x1 = s_a[(r0 + 1) * 256 + d];
      acc[0][0] += x0 * w.x; acc[0][1] += x0 * w.y; acc[0][2] += x0 * w.z; acc[0][3] += x0 * w.w;
      acc[1][0] += x1 * w.x; acc[1][1] += x1 * w.y; acc[1][2] += x1 * w.z; acc[1][3] += x1 * w.w;
    }
    float4 bb = ((const float4*)bp)[tx];
#pragma unroll
    for (int rr = 0; rr < 2; ++rr) {
      int r = r0 + rr;
      s_z[r * 260 + j + 0] = acc[rr][0] + bb.x + skip[(size_t)(j + 0) * QL + q0 + r];
      s_z[r * 260 + j + 1] = acc[rr][1] + bb.y + skip[(size_t)(j + 1) * QL + q0 + r];
      s_z[r * 260 + j + 2] = acc[rr][2] + bb.z + skip[(size_t)(j + 2) * QL + q0 + r];
      s_z[r * 260 + j + 3] = acc[rr][3] + bb.w + skip[(size_t)(j + 3) * QL + q0 + r];
    }
  }
  __syncthreads();

  ln_rows8(s_z, 260, lng1, lnb1, t);
  __syncthreads();

  {
    float acc[2][8] = {{0,0,0,0,0,0,0,0},{0,0,0,0,0,0,0,0}};
    const float4* W4 = (const float4*)w1;
    for (int d = 0; d < 256; ++d) {
      float4 wa = W4[d * 128 + tx];
      float4 wb = W4[d * 128 + 64 + tx];
      float x0 = s_z[r0 * 260 + d];
      float x1 = s_z[(r0 + 1) * 260 + d];
      acc[0][0] += x0 * wa.x; acc[0][1] += x0 * wa.y; acc[0][2] += x0 * wa.z; acc[0][3] += x0 * wa.w;
      acc[0][4] += x0 * wb.x; acc[0][5] += x0 * wb.y; acc[0][6] += x0 * wb.z; acc[0][7] += x0 * wb.w;
      acc[1][0] += x1 * wa.x; acc[1][1] += x1 * wa.y; acc[1][2] += x1 * wa.z; acc[1][3] += x1 * wa.w;
      acc[1][4] += x1 * wb.x; acc[1][5] += x1 * wb.y; acc[1][6] += x1 * wb.z; acc[1][7] += x1 * wb.w;
    }
#pragma unroll
    for (int rr = 0; rr < 2; ++rr) {
      int r = r0 + rr;
#pragma unroll
      for (int pp = 0; pp < 2; ++pp) {
#pragma unroll
        for (int c = 0; c < 4; ++c) {
          int jj = 4 * tx + 256 * pp + c;
          float val = acc[rr][pp * 4 + c] + b1[jj];
          s_h[r * 516 + jj] = 0.5f * val * (1.f + erff(val * 0.70710678118654752f));
        }
      }
    }
  }
  __syncthreads();

  {
    float acc[2][4] = {{0.f,0.f,0.f,0.f},{0.f,0.f,0.f,0.f}};
    const float4* W4 = (const float4*)w2;
    for (int d = 0; d < 512; ++d) {
      float4 w = W4[d * 64 + tx];
      float x0 = s_h[r0 * 516 + d];
      float x1 = s_h[(r0 + 1) * 516 + d];
      acc[0][0] += x0 * w.x; acc[0][1] += x0 * w.y; acc[0][2] += x0 * w.z; acc[0][3] += x0 * w.w;
      acc[1][0] += x1 * w.x; acc[1][1] += x1 * w.y; acc[1][2] += x1 * w.z; acc[1][3] += x1 * w.w;
    }
    float4 bb = ((const float4*)b2)[tx];
#pragma unroll
    for (int rr = 0; rr < 2; ++rr) {
      int r = r0 + rr;
      s_a[r * 256 + j + 0] = s_z[r * 260 + j + 0] + acc[rr][0] + bb.x;
      s_a[r * 256 + j + 1] = s_z[r * 260 + j + 1] + acc[rr][1] + bb.y;
      s_a[r * 256 + j + 2] = s_z[r * 260 + j + 2] + acc[rr][2] + bb.z;
      s_a[r * 256 + j + 3] = s_z[r * 260 + j + 3] + acc[rr][3] + bb.w;
    }
  }
  __syncthreads();

  {
    int r = t >> 5, l = t & 31;
    float s = 0.f, s2 = 0.f;
#pragma unroll
    for (int kk = 0; kk < 8; ++kk) {
      float x = s_a[r * 256 + l + 32 * kk];
      s += x; s2 += x * x;
    }
#pragma unroll
    for (int m = 16; m >= 1; m >>= 1) {
      s += __shfl_xor(s, m, 64); s2 += __shfl_xor(s2, m, 64);
    }
    float mu = s * (1.f / 256.f);
    float var = s2 * (1.f / 256.f) - mu * mu;
    float istd = rsqrtf(var + EPSLN);
#pragma unroll
    for (int kk = 0; kk < 8; ++kk) {
      int d = l + 32 * kk;
      float val = (s_a[r * 256 + d] - mu) * istd * lng2[d] + lnb2[d];
      out[(size_t)d * QL + q0 + r] = val;
    }
  }
}

extern "C" void kernel_launch(void* const* d_in, const int* in_sizes, int n_in,
                              void* d_out, int out_size, void* d_ws, size_t ws_size,
                              hipStream_t stream) {
  (void)in_sizes; (void)n_in; (void)out_size; (void)ws_size;
  const float* q     = (const float*)d_in[0];
  const float* k     = (const float*)d_in[1];
  const float* v     = (const float*)d_in[2];
  const float* skip  = (const float*)d_in[3];
  const int*   mask  = (const int*)d_in[4];
  const float* lnqg  = (const float*)d_in[5];
  const float* lnqb  = (const float*)d_in[6];
  const float* wq    = (const float*)d_in[7];
  const float* bq    = (const float*)d_in[8];
  const float* lnkg  = (const float*)d_in[9];
  const float* lnkb  = (const float*)d_in[10];
  const float* wk    = (const float*)d_in[11];
  const float* bk    = (const float*)d_in[12];
  const float* lnvg  = (const float*)d_in[13];
  const float* lnvb  = (const float*)d_in[14];
  const float* wv    = (const float*)d_in[15];
  const float* bv    = (const float*)d_in[16];
  const float* wp    = (const float*)d_in[17];
  const float* bp    = (const float*)d_in[18];
  const float* lng1  = (const float*)d_in[19];
  const float* lnb1  = (const float*)d_in[20];
  const float* w1    = (const float*)d_in[21];
  const float* b1    = (const float*)d_in[22];
  const float* w2    = (const float*)d_in[23];
  const float* b2    = (const float*)d_in[24];
  const float* lng2  = (const float*)d_in[25];
  const float* lnb2  = (const float*)d_in[26];
  float* out = (float*)d_out;

  unsigned char* ws = (unsigned char*)d_ws;
  unsigned short* ws16 = (unsigned short*)d_ws;
  unsigned short* wqT = (unsigned short*)(ws + OFF_WQT);
  unsigned short* wkT = (unsigned short*)(ws + OFF_WKT);
  unsigned short* wvT = (unsigned short*)(ws + OFF_WVT);
  unsigned short* qh  = (unsigned short*)(ws + OFF_QH);
  unsigned short* pbuf= (unsigned short*)(ws + OFF_PBUF);
  float* attg = (float*)(ws + OFF_ATT);
  float* aws  = (float*)(ws + OFF_AWS);

  hipLaunchKernelGGL(prep_kernel, dim3(6), dim3(256), 0, stream, wq, wk, wv, ws16);
  hipLaunchKernelGGL(proj_kernel, dim3(192), dim3(256), 0, stream,
                     q, lnqg, lnqb, wqT, bq, qh, 1);
  hipLaunchKernelGGL(proj_kernel, dim3(1536), dim3(256), 0, stream,
                     k, lnkg, lnkb, wkT, bk, pbuf, 0);
  hipLaunchKernelGGL(score_kernel, dim3(QL), dim3(256), 0, stream,
                     qh, pbuf, mask, attg);
  hipLaunchKernelGGL(proj_kernel, dim3(1536), dim3(256), 0, stream,
                     v, lnvg, lnvb, wvT, bv, pbuf, 0);
  hipLaunchKernelGGL(pv_kernel, dim3(QL), dim3(256), 0, stream,
                     pbuf, attg, aws);
  hipLaunchKernelGGL(epi_kernel, dim3(QL / 8), dim3(256), 0, stream,
                     aws, skip, wp, bp, lng1, lnb1, w1, b1, w2, b2, lng2, lnb2, out);
}

// Round 3
// 722.976 us; speedup vs baseline: 2.1706x; 1.1164x over previous
//
#include <hip/hip_runtime.h>
#include <hip/hip_bf16.h>
#include <math.h>

#define NF 6
#define GG 8
#define NG 48
#define QL 4096
#define DIMC 256
#define NHEAD 4
#define DHEAD 64
#define SCALE 0.125f
#define EPSLN 1e-5f

#define LDPAD 264   // bf16 elems/row pad
#define FPAD  264   // f32 elems/row pad (264*4=1056, 16B-aligned rows)
#define HPAD  528   // bf16 elems/row for 512-wide h (528*2=1056)

typedef __bf16 bf16x8 __attribute__((ext_vector_type(8)));
typedef float  f32x4  __attribute__((ext_vector_type(4)));

// ---- workspace layout (bytes) ----
#define OFF_WQT   0u
#define OFF_WKT   131072u
#define OFF_WVT   262144u
#define OFF_WPT   393216u
#define OFF_W1T   524288u     // 512x256 bf16 = 256 KB
#define OFF_W2T   786432u     // 256x512 bf16 = 256 KB
#define OFF_QH    1048576u    // 24576 x 256 bf16 = 12.58 MB
#define OFF_ATT   13631488u   // 4096 x 4 x 48 f32 = 3.15 MB
#define OFF_OPART 16777216u   // 6 x 4096 x 256 f32 = 25.17 MB

__device__ __forceinline__ unsigned short f2bf(float x) {
  union { float f; unsigned u; } v; v.f = x;
  unsigned r = v.u + 0x7FFFu + ((v.u >> 16) & 1u);
  return (unsigned short)(r >> 16);
}

// ================= prep: f32 W[K][N] -> bf16 W^T[N][K] (all 6 matrices) ====
__global__ void __launch_bounds__(256)
prep2_kernel(const float* __restrict__ wq, const float* __restrict__ wk,
             const float* __restrict__ wvv, const float* __restrict__ wp,
             const float* __restrict__ w1, const float* __restrict__ w2,
             unsigned short* __restrict__ wsu16)
{
  __shared__ __align__(16) unsigned short s_t[64 * HPAD];
  const int blk = blockIdx.x, t = threadIdx.x;
  const float* src; unsigned short* dst; int N, K, n0, rs;
  if (blk < 16) {
    int mi = blk >> 2; n0 = (blk & 3) * 64; N = 256; K = 256; rs = 9;
    src = (mi == 0) ? wq : (mi == 1) ? wk : (mi == 2) ? wvv : wp;
    dst = wsu16 + (size_t)mi * 65536;
  } else if (blk < 24) {
    n0 = (blk - 16) * 64; N = 512; K = 256; rs = 9;
    src = w1; dst = wsu16 + OFF_W1T / 2;
  } else {
    n0 = (blk - 24) * 64; N = 256; K = 512; rs = 10;
    src = w2; dst = wsu16 + OFF_W2T / 2;
  }
  const int nn = t & 63, dq = t >> 6;
  for (int d0 = 0; d0 < K; d0 += 4) {
    int d = d0 + dq;
    s_t[nn * HPAD + d] = f2bf(src[(size_t)d * N + n0 + nn]);
  }
  __syncthreads();
  const int rowbytes = K * 2;
  const int total = 64 * rowbytes;
  unsigned char* db = (unsigned char*)(dst + (size_t)n0 * K);
  for (int lin = t * 16; lin < total; lin += 4096) {
    int r = lin >> rs;            // rowbytes = 1<<rs
    int off = lin & (rowbytes - 1);
    uint4 vv = *(const uint4*)((const unsigned char*)s_t + r * (HPAD * 2) + off);
    *(uint4*)(db + lin) = vv;
  }
}

// ================= proj-q: gather-transpose + LN + MFMA -> qh bf16 =========
// (structure verified in round 2; 128-pixel tiles, grid 192)
__global__ void __launch_bounds__(256, 2)
projq_kernel(const float* __restrict__ src,
             const float* __restrict__ lng, const float* __restrict__ lnb,
             const unsigned short* __restrict__ wT,
             const float* __restrict__ bias,
             unsigned short* __restrict__ outp)
{
  __shared__ __align__(16) unsigned short s_x[128 * LDPAD];
  __shared__ float s_bias[256];
  const int t = threadIdx.x;
  const int blk = blockIdx.x;
  s_bias[t] = bias[t];

  const int n = blk >> 5, qp0 = (blk & 31) << 7;
  const int l32 = t & 31;
  for (int it = 0; it < 32; ++it) {
    int dcol = it * 8 + (t >> 5);
    float4 x = *(const float4*)(src + ((size_t)(n * 256 + dcol)) * 4096 + qp0 + l32 * 4);
    s_x[(l32 * 4 + 0) * LDPAD + dcol] = f2bf(x.x);
    s_x[(l32 * 4 + 1) * LDPAD + dcol] = f2bf(x.y);
    s_x[(l32 * 4 + 2) * LDPAD + dcol] = f2bf(x.z);
    s_x[(l32 * 4 + 3) * LDPAD + dcol] = f2bf(x.w);
  }
  __syncthreads();
  {
    const int row = t >> 1, half = t & 1;
    bf16x8 rv[16];
    float s = 0.f, s2 = 0.f;
#pragma unroll
    for (int i = 0; i < 16; ++i) {
      rv[i] = *(const bf16x8*)(s_x + row * LDPAD + half * 128 + i * 8);
#pragma unroll
      for (int j = 0; j < 8; ++j) { float xf = (float)rv[i][j]; s += xf; s2 += xf * xf; }
    }
    s  += __shfl_xor(s, 1, 64);
    s2 += __shfl_xor(s2, 1, 64);
    float mu  = s * (1.f / 256.f);
    float var = s2 * (1.f / 256.f) - mu * mu;
    float istd = rsqrtf(var + EPSLN);
#pragma unroll
    for (int i = 0; i < 16; ++i) {
      float4 ga = *(const float4*)(lng + half * 128 + i * 8);
      float4 gb = *(const float4*)(lng + half * 128 + i * 8 + 4);
      float4 ba = *(const float4*)(lnb + half * 128 + i * 8);
      float4 bb = *(const float4*)(lnb + half * 128 + i * 8 + 4);
      float gs[8] = {ga.x, ga.y, ga.z, ga.w, gb.x, gb.y, gb.z, gb.w};
      float bs[8] = {ba.x, ba.y, ba.z, ba.w, bb.x, bb.y, bb.z, bb.w};
      unsigned dw[4];
#pragma unroll
      for (int j = 0; j < 4; ++j) {
        unsigned short lo = f2bf(((float)rv[i][2 * j]     - mu) * istd * gs[2 * j]     + bs[2 * j]);
        unsigned short hi = f2bf(((float)rv[i][2 * j + 1] - mu) * istd * gs[2 * j + 1] + bs[2 * j + 1]);
        dw[j] = (unsigned)lo | ((unsigned)hi << 16);
      }
      uint4 u4 = make_uint4(dw[0], dw[1], dw[2], dw[3]);
      *(uint4*)(s_x + row * LDPAD + half * 128 + i * 8) = u4;
    }
  }
  __syncthreads();

  const int wv_ = t >> 6, lane = t & 63;
  const int nhalf = wv_ & 1, mhalf = wv_ >> 1;
  const int lr = lane & 15, quad = lane >> 4;
  f32x4 acc[8][4];
  {
    f32x4 z = {0.f, 0.f, 0.f, 0.f};
#pragma unroll
    for (int a = 0; a < 8; ++a)
#pragma unroll
      for (int b = 0; b < 4; ++b) acc[a][b] = z;
  }
  for (int kt = 0; kt < 8; ++kt) {
    bf16x8 xf[4], wf[8];
#pragma unroll
    for (int mt = 0; mt < 4; ++mt)
      xf[mt] = *(const bf16x8*)(s_x + (mhalf * 64 + mt * 16 + lr) * LDPAD + kt * 32 + quad * 8);
#pragma unroll
    for (int nt = 0; nt < 8; ++nt)
      wf[nt] = *(const bf16x8*)(wT + ((nhalf * 128 + nt * 16 + lr) * 256 + kt * 32 + quad * 8));
#pragma unroll
    for (int nt = 0; nt < 8; ++nt)
#pragma unroll
      for (int mt = 0; mt < 4; ++mt)
        acc[nt][mt] = __builtin_amdgcn_mfma_f32_16x16x32_bf16(wf[nt], xf[mt], acc[nt][mt], 0, 0, 0);
  }
  __syncthreads();

#pragma unroll
  for (int nt = 0; nt < 8; ++nt) {
    int n0 = nhalf * 128 + nt * 16 + quad * 4;
    float4 bb = *(const float4*)(s_bias + n0);
#pragma unroll
    for (int mt = 0; mt < 4; ++mt) {
      int m = mhalf * 64 + mt * 16 + lr;
      f32x4 a = acc[nt][mt];
      unsigned d0 = (unsigned)f2bf(a[0] + bb.x) | ((unsigned)f2bf(a[1] + bb.y) << 16);
      unsigned d1 = (unsigned)f2bf(a[2] + bb.z) | ((unsigned)f2bf(a[3] + bb.w) << 16);
      unsigned long long dd = (unsigned long long)d0 | ((unsigned long long)d1 << 32);
      *(unsigned long long*)(s_x + m * LDPAD + n0) = dd;
    }
  }
  __syncthreads();

  unsigned char* ob = (unsigned char*)outp + (size_t)blk * 65536;
#pragma unroll
  for (int i = 0; i < 16; ++i) {
    int lin = i * 4096 + t * 16;
    int r = lin >> 9, off = lin & 511;
    uint4 v = *(const uint4*)((const unsigned char*)s_x + r * (LDPAD * 2) + off);
    *(uint4*)(ob + lin) = v;
  }
}

// ====== fused proj k/v: 64 rows (8 px x 8 g, one frame) + score or PV ======
__global__ void __launch_bounds__(256, 4)
projkv_kernel(const float* __restrict__ src,
              const float* __restrict__ lng, const float* __restrict__ lnb,
              const unsigned short* __restrict__ wT,
              const float* __restrict__ bias,
              const unsigned short* __restrict__ qh,
              float* __restrict__ attg,
              float* __restrict__ opart,
              int kind)   // 0 = K-side (scores), 1 = V-side (PV partials)
{
  __shared__ __align__(16) unsigned short s_x[64 * LDPAD];
  __shared__ float s_bias[256];
  const int t = threadIdx.x, blk = blockIdx.x;
  const int n = blk >> 9, qp0 = (blk & 511) << 3;
  s_bias[t] = bias[t];

  // ---- stage + LN (4 threads/row) ----
  {
    const int row = t >> 2, sl = t & 3;
    const float4* rp = (const float4*)(src + ((size_t)blk * 64 + row) * 256) + sl;
    float4 dat[16];
    float s = 0.f, s2 = 0.f;
#pragma unroll
    for (int i = 0; i < 16; ++i) {
      float4 x = rp[i * 4]; dat[i] = x;
      s  += x.x + x.y + x.z + x.w;
      s2 += x.x * x.x + x.y * x.y + x.z * x.z + x.w * x.w;
    }
    s  += __shfl_xor(s, 1, 64);  s  += __shfl_xor(s, 2, 64);
    s2 += __shfl_xor(s2, 1, 64); s2 += __shfl_xor(s2, 2, 64);
    float mu  = s * (1.f / 256.f);
    float var = s2 * (1.f / 256.f) - mu * mu;
    float istd = rsqrtf(var + EPSLN);
    const float4* g4 = (const float4*)lng;
    const float4* b4 = (const float4*)lnb;
#pragma unroll
    for (int i = 0; i < 16; ++i) {
      int c = sl + 4 * i;
      float4 gv = g4[c], bv = b4[c], x = dat[i];
      unsigned d0 = (unsigned)f2bf((x.x - mu) * istd * gv.x + bv.x) |
                    ((unsigned)f2bf((x.y - mu) * istd * gv.y + bv.y) << 16);
      unsigned d1 = (unsigned)f2bf((x.z - mu) * istd * gv.z + bv.z) |
                    ((unsigned)f2bf((x.w - mu) * istd * gv.w + bv.w) << 16);
      unsigned long long dd = (unsigned long long)d0 | ((unsigned long long)d1 << 32);
      *(unsigned long long*)(s_x + row * LDPAD + c * 4) = dd;
    }
  }
  __syncthreads();

  // ---- MFMA: wave tile M=32, N=128 ----
  const int wv_ = t >> 6, lane = t & 63;
  const int mhalf = wv_ >> 1, nhalf = wv_ & 1;
  const int lr = lane & 15, quad = lane >> 4;
  f32x4 acc[8][2];
  {
    f32x4 z = {0.f, 0.f, 0.f, 0.f};
#pragma unroll
    for (int a = 0; a < 8; ++a) { acc[a][0] = z; acc[a][1] = z; }
  }
  for (int kt = 0; kt < 8; ++kt) {
    bf16x8 xf[2], wf[8];
#pragma unroll
    for (int mt = 0; mt < 2; ++mt)
      xf[mt] = *(const bf16x8*)(s_x + (mhalf * 32 + mt * 16 + lr) * LDPAD + kt * 32 + quad * 8);
#pragma unroll
    for (int nt = 0; nt < 8; ++nt)
      wf[nt] = *(const bf16x8*)(wT + ((nhalf * 128 + nt * 16 + lr) * 256 + kt * 32 + quad * 8));
#pragma unroll
    for (int nt = 0; nt < 8; ++nt)
#pragma unroll
      for (int mt = 0; mt < 2; ++mt)
        acc[nt][mt] = __builtin_amdgcn_mfma_f32_16x16x32_bf16(wf[nt], xf[mt], acc[nt][mt], 0, 0, 0);
  }
  __syncthreads();   // s_x -> projected tile stage

#pragma unroll
  for (int nt = 0; nt < 8; ++nt) {
    int n0 = nhalf * 128 + nt * 16 + quad * 4;
    float4 bb = *(const float4*)(s_bias + n0);
#pragma unroll
    for (int mt = 0; mt < 2; ++mt) {
      int m = mhalf * 32 + mt * 16 + lr;
      f32x4 a = acc[nt][mt];
      unsigned d0 = (unsigned)f2bf(a[0] + bb.x) | ((unsigned)f2bf(a[1] + bb.y) << 16);
      unsigned d1 = (unsigned)f2bf(a[2] + bb.z) | ((unsigned)f2bf(a[3] + bb.w) << 16);
      unsigned long long dd = (unsigned long long)d0 | ((unsigned long long)d1 << 32);
      *(unsigned long long*)(s_x + m * LDPAD + n0) = dd;
    }
  }
  __syncthreads();

  if (kind == 0) {
    // scores: thread -> (p, m, g); dot(qh[n,p,m,:64], kh[p,g,m,:64])
    const int p = t >> 5, m = (t >> 3) & 3, g = t & 7;
    const unsigned short* kr = s_x + (p * 8 + g) * LDPAD + m * 64;
    const unsigned short* qr = qh + ((size_t)(n * QL) + qp0 + p) * 256 + m * 64;
    float dot = 0.f;
#pragma unroll
    for (int i = 0; i < 8; ++i) {
      bf16x8 kv = *(const bf16x8*)(kr + i * 8);
      bf16x8 qv = *(const bf16x8*)(qr + i * 8);
#pragma unroll
      for (int j = 0; j < 8; ++j) dot += (float)kv[j] * (float)qv[j];
    }
    attg[(((size_t)(qp0 + p)) * 4 + m) * 48 + n * 8 + g] = dot * SCALE;
  } else {
    // PV partial: thread -> (p, 8 cols); O[p][c0..+8] = sum_g att * vh
    const int p = t >> 5, c0 = (t & 31) * 8, m = c0 >> 6;
    const float4* ar = (const float4*)(attg + (((size_t)(qp0 + p)) * 4 + m) * 48 + n * 8);
    float4 a0 = ar[0], a1 = ar[1];
    float aw[8] = {a0.x, a0.y, a0.z, a0.w, a1.x, a1.y, a1.z, a1.w};
    float o[8] = {0.f, 0.f, 0.f, 0.f, 0.f, 0.f, 0.f, 0.f};
#pragma unroll
    for (int g = 0; g < 8; ++g) {
      bf16x8 vvv = *(const bf16x8*)(s_x + (p * 8 + g) * LDPAD + c0);
#pragma unroll
      for (int j = 0; j < 8; ++j) o[j] += aw[g] * (float)vvv[j];
    }
    float4* op = (float4*)(opart + ((size_t)n * QL + qp0 + p) * 256 + c0);
    op[0] = make_float4(o[0], o[1], o[2], o[3]);
    op[1] = make_float4(o[4], o[5], o[6], o[7]);
  }
}

// ================= softmax + mask over 48 keys per (pixel, head) ===========
__global__ void __launch_bounds__(256)
softmax_kernel(float* __restrict__ attg, const int* __restrict__ mask)
{
  const int tg = blockIdx.x * 256 + threadIdx.x;   // 0..16383
  const int p = tg >> 2;
  float* row = attg + (size_t)tg * 48;
  float xs[48];
#pragma unroll
  for (int i = 0; i < 12; ++i) {
    float4 x = ((const float4*)row)[i];
    xs[4 * i] = x.x; xs[4 * i + 1] = x.y; xs[4 * i + 2] = x.z; xs[4 * i + 3] = x.w;
  }
#pragma unroll
  for (int n = 0; n < 6; ++n) {
    if (!mask[n * QL + p]) {
#pragma unroll
      for (int j = 0; j < 8; ++j) xs[n * 8 + j] = -1e9f;
    }
  }
  float mx = -3.0e38f;
#pragma unroll
  for (int i = 0; i < 48; ++i) mx = fmaxf(mx, xs[i]);
  float sm = 0.f;
#pragma unroll
  for (int i = 0; i < 48; ++i) { float e = __expf(xs[i] - mx); xs[i] = e; sm += e; }
  float inv = 1.f / sm;
#pragma unroll
  for (int i = 0; i < 12; ++i)
    ((float4*)row)[i] = make_float4(xs[4 * i] * inv, xs[4 * i + 1] * inv,
                                    xs[4 * i + 2] * inv, xs[4 * i + 3] * inv);
}

// ================= epilogue: MFMA proj + skip + LN + MLP + LN ==============
__global__ void __launch_bounds__(256)
epi_kernel(const float* __restrict__ opart, const float* __restrict__ skip,
           const unsigned short* __restrict__ wpT, const float* __restrict__ bp,
           const float* __restrict__ lng1, const float* __restrict__ lnb1,
           const unsigned short* __restrict__ w1T, const float* __restrict__ b1,
           const unsigned short* __restrict__ w2T, const float* __restrict__ b2,
           const float* __restrict__ lng2, const float* __restrict__ lnb2,
           float* __restrict__ out)
{
  __shared__ __align__(16) unsigned short s_a[16 * LDPAD];
  __shared__ __align__(16) float s_sk[16 * FPAD];
  __shared__ __align__(16) float s_z[16 * FPAD];
  __shared__ __align__(16) unsigned short s_zb[16 * LDPAD];
  __shared__ __align__(16) unsigned short s_h[16 * HPAD];
  __shared__ __align__(16) float s_z2[16 * FPAD];
  const int t = threadIdx.x, q0 = blockIdx.x * 16;

  // stage a = sum_n opart[n], as bf16
#pragma unroll
  for (int i = 0; i < 16; ++i) {
    int idx = i * 256 + t, p = idx >> 8, c = idx & 255;
    size_t base = ((size_t)(q0 + p)) * 256 + c;
    float s = 0.f;
#pragma unroll
    for (int nn = 0; nn < 6; ++nn) s += opart[(size_t)nn * (QL * 256) + base];
    s_a[p * LDPAD + c] = f2bf(s);
  }
  // stage skip tile (transposed read)
#pragma unroll
  for (int i = 0; i < 16; ++i) {
    int c = i * 16 + (t >> 4), p = t & 15;
    s_sk[p * FPAD + c] = skip[(size_t)c * QL + q0 + p];
  }
  __syncthreads();

  const int lane = t & 63, lr = lane & 15, quad = lane >> 4, wv_ = t >> 6;

  // GEMM1: z = a @ wp + bp + skip   (N=256, wave covers 64 cols)
  {
    f32x4 acc[4];
    f32x4 z = {0.f, 0.f, 0.f, 0.f};
#pragma unroll
    for (int a = 0; a < 4; ++a) acc[a] = z;
    for (int kt = 0; kt < 8; ++kt) {
      bf16x8 xf = *(const bf16x8*)(s_a + lr * LDPAD + kt * 32 + quad * 8);
      bf16x8 wf[4];
#pragma unroll
      for (int nt = 0; nt < 4; ++nt)
        wf[nt] = *(const bf16x8*)(wpT + ((wv_ * 64 + nt * 16 + lr) * 256 + kt * 32 + quad * 8));
#pragma unroll
      for (int nt = 0; nt < 4; ++nt)
        acc[nt] = __builtin_amdgcn_mfma_f32_16x16x32_bf16(wf[nt], xf, acc[nt], 0, 0, 0);
    }
#pragma unroll
    for (int nt = 0; nt < 4; ++nt) {
      int n0 = wv_ * 64 + nt * 16 + quad * 4;
      f32x4 bb = *(const f32x4*)(bp + n0);
      f32x4 sk = *(const f32x4*)(s_sk + lr * FPAD + n0);
      *(f32x4*)(s_z + lr * FPAD + n0) = acc[nt] + bb + sk;
    }
  }
  __syncthreads();

  // LN1 (normalize in place + bf16 copy)
  {
    int r = t >> 4, l = t & 15;
    float s = 0.f, s2 = 0.f;
#pragma unroll
    for (int i = 0; i < 16; ++i) {
      float x = s_z[r * FPAD + l + 16 * i];
      s += x; s2 += x * x;
    }
    s += __shfl_xor(s, 1, 64); s += __shfl_xor(s, 2, 64);
    s += __shfl_xor(s, 4, 64); s += __shfl_xor(s, 8, 64);
    s2 += __shfl_xor(s2, 1, 64); s2 += __shfl_xor(s2, 2, 64);
    s2 += __shfl_xor(s2, 4, 64); s2 += __shfl_xor(s2, 8, 64);
    float mu = s * (1.f / 256.f);
    float var = s2 * (1.f / 256.f) - mu * mu;
    float istd = rsqrtf(var + EPSLN);
#pragma unroll
    for (int i = 0; i < 16; ++i) {
      int d = l + 16 * i;
      float nv = (s_z[r * FPAD + d] - mu) * istd * lng1[d] + lnb1[d];
      s_z[r * FPAD + d] = nv;
      s_zb[r * LDPAD + d] = f2bf(nv);
    }
  }
  __syncthreads();

  // GEMM2: h = gelu(z @ w1 + b1)   (N=512, wave covers 128 cols)
  {
    f32x4 acc[8];
    f32x4 z = {0.f, 0.f, 0.f, 0.f};
#pragma unroll
    for (int a = 0; a < 8; ++a) acc[a] = z;
    for (int kt = 0; kt < 8; ++kt) {
      bf16x8 xf = *(const bf16x8*)(s_zb + lr * LDPAD + kt * 32 + quad * 8);
      bf16x8 wf[8];
#pragma unroll
      for (int nt = 0; nt < 8; ++nt)
        wf[nt] = *(const bf16x8*)(w1T + ((wv_ * 128 + nt * 16 + lr) * 256 + kt * 32 + quad * 8));
#pragma unroll
      for (int nt = 0; nt < 8; ++nt)
        acc[nt] = __builtin_amdgcn_mfma_f32_16x16x32_bf16(wf[nt], xf, acc[nt], 0, 0, 0);
    }
#pragma unroll
    for (int nt = 0; nt < 8; ++nt) {
      int n0 = wv_ * 128 + nt * 16 + quad * 4;
      f32x4 bb = *(const f32x4*)(b1 + n0);
      unsigned short hv[4];
#pragma unroll
      for (int j = 0; j < 4; ++j) {
        float val = acc[nt][j] + bb[j];
        hv[j] = f2bf(0.5f * val * (1.f + erff(val * 0.70710678118654752f)));
      }
      unsigned long long dd = (unsigned long long)((unsigned)hv[0] | ((unsigned)hv[1] << 16)) |
                              ((unsigned long long)((unsigned)hv[2] | ((unsigned)hv[3] << 16)) << 32);
      *(unsigned long long*)(s_h + lr * HPAD + n0) = dd;
    }
  }
  __syncthreads();

  // GEMM3: z2 = z + h @ w2 + b2   (N=256, K=512)
  {
    f32x4 acc[4];
    f32x4 z = {0.f, 0.f, 0.f, 0.f};
#pragma unroll
    for (int a = 0; a < 4; ++a) acc[a] = z;
    for (int kt = 0; kt < 16; ++kt) {
      bf16x8 xf = *(const bf16x8*)(s_h + lr * HPAD + kt * 32 + quad * 8);
      bf16x8 wf[4];
#pragma unroll
      for (int nt = 0; nt < 4; ++nt)
        wf[nt] = *(const bf16x8*)(w2T + ((wv_ * 64 + nt * 16 + lr) * 512 + kt * 32 + quad * 8));
#pragma unroll
      for (int nt = 0; nt < 4; ++nt)
        acc[nt] = __builtin_amdgcn_mfma_f32_16x16x32_bf16(wf[nt], xf, acc[nt], 0, 0, 0);
    }
#pragma unroll
    for (int nt = 0; nt < 4; ++nt) {
      int n0 = wv_ * 64 + nt * 16 + quad * 4;
      f32x4 bb = *(const f32x4*)(b2 + n0);
      f32x4 zr = *(const f32x4*)(s_z + lr * FPAD + n0);
      *(f32x4*)(s_z2 + lr * FPAD + n0) = acc[nt] + bb + zr;
    }
  }
  __syncthreads();

  // LN2 (in place)
  {
    int r = t >> 4, l = t & 15;
    float s = 0.f, s2 = 0.f;
#pragma unroll
    for (int i = 0; i < 16; ++i) {
      float x = s_z2[r * FPAD + l + 16 * i];
      s += x; s2 += x * x;
    }
    s += __shfl_xor(s, 1, 64); s += __shfl_xor(s, 2, 64);
    s += __shfl_xor(s, 4, 64); s += __shfl_xor(s, 8, 64);
    s2 += __shfl_xor(s2, 1, 64); s2 += __shfl_xor(s2, 2, 64);
    s2 += __shfl_xor(s2, 4, 64); s2 += __shfl_xor(s2, 8, 64);
    float mu = s * (1.f / 256.f);
    float var = s2 * (1.f / 256.f) - mu * mu;
    float istd = rsqrtf(var + EPSLN);
#pragma unroll
    for (int i = 0; i < 16; ++i) {
      int d = l + 16 * i;
      s_z2[r * FPAD + d] = (s_z2[r * FPAD + d] - mu) * istd * lng2[d] + lnb2[d];
    }
  }
  __syncthreads();

  // transposed store: out[d][q0+p]
#pragma unroll
  for (int i = 0; i < 16; ++i) {
    int c = i * 16 + (t >> 4), p = t & 15;
    out[(size_t)c * QL + q0 + p] = s_z2[p * FPAD + c];
  }
}

extern "C" void kernel_launch(void* const* d_in, const int* in_sizes, int n_in,
                              void* d_out, int out_size, void* d_ws, size_t ws_size,
                              hipStream_t stream) {
  (void)in_sizes; (void)n_in; (void)out_size; (void)ws_size;
  const float* q     = (const float*)d_in[0];
  const float* k     = (const float*)d_in[1];
  const float* v     = (const float*)d_in[2];
  const float* skip  = (const float*)d_in[3];
  const int*   mask  = (const int*)d_in[4];
  const float* lnqg  = (const float*)d_in[5];
  const float* lnqb  = (const float*)d_in[6];
  const float* wq    = (const float*)d_in[7];
  const float* bq    = (const float*)d_in[8];
  const float* lnkg  = (const float*)d_in[9];
  const float* lnkb  = (const float*)d_in[10];
  const float* wk    = (const float*)d_in[11];
  const float* bk    = (const float*)d_in[12];
  const float* lnvg  = (const float*)d_in[13];
  const float* lnvb  = (const float*)d_in[14];
  const float* wv    = (const float*)d_in[15];
  const float* bv    = (const float*)d_in[16];
  const float* wp    = (const float*)d_in[17];
  const float* bp    = (const float*)d_in[18];
  const float* lng1  = (const float*)d_in[19];
  const float* lnb1  = (const float*)d_in[20];
  const float* w1    = (const float*)d_in[21];
  const float* b1    = (const float*)d_in[22];
  const float* w2    = (const float*)d_in[23];
  const float* b2    = (const float*)d_in[24];
  const float* lng2  = (const float*)d_in[25];
  const float* lnb2  = (const float*)d_in[26];
  float* out = (float*)d_out;

  unsigned char* ws = (unsigned char*)d_ws;
  unsigned short* wsu16 = (unsigned short*)d_ws;
  unsigned short* wqT = (unsigned short*)(ws + OFF_WQT);
  unsigned short* wkT = (unsigned short*)(ws + OFF_WKT);
  unsigned short* wvT = (unsigned short*)(ws + OFF_WVT);
  unsigned short* wpT = (unsigned short*)(ws + OFF_WPT);
  unsigned short* w1T = (unsigned short*)(ws + OFF_W1T);
  unsigned short* w2T = (unsigned short*)(ws + OFF_W2T);
  unsigned short* qh  = (unsigned short*)(ws + OFF_QH);
  float* attg  = (float*)(ws + OFF_ATT);
  float* opart = (float*)(ws + OFF_OPART);

  hipLaunchKernelGGL(prep2_kernel, dim3(28), dim3(256), 0, stream,
                     wq, wk, wv, wp, w1, w2, wsu16);
  hipLaunchKernelGGL(projq_kernel, dim3(192), dim3(256), 0, stream,
                     q, lnqg, lnqb, wqT, bq, qh);
  hipLaunchKernelGGL(projkv_kernel, dim3(3072), dim3(256), 0, stream,
                     k, lnkg, lnkb, wkT, bk, qh, attg, opart, 0);
  hipLaunchKernelGGL(softmax_kernel, dim3(64), dim3(256), 0, stream,
                     attg, mask);
  hipLaunchKernelGGL(projkv_kernel, dim3(3072), dim3(256), 0, stream,
                     v, lnvg, lnvb, wvT, bv, qh, attg, opart, 1);
  hipLaunchKernelGGL(epi_kernel, dim3(QL / 16), dim3(256), 0, stream,
                     opart, skip, wpT, bp, lng1, lnb1, w1T, b1, w2T, b2, lng2, lnb2, out);
}

// Round 4
// 571.070 us; speedup vs baseline: 2.7480x; 1.2660x over previous
//
#include <hip/hip_runtime.h>
#include <hip/hip_bf16.h>
#include <math.h>

#define NF 6
#define QL 4096
#define SCALE 0.125f
#define EPSLN 1e-5f

typedef __bf16 bf16x8 __attribute__((ext_vector_type(8)));
typedef __bf16 bf16x4 __attribute__((ext_vector_type(4)));
typedef float  f32x4  __attribute__((ext_vector_type(4)));

// ---- workspace layout (bytes) ----
#define OFF_WQT   0u
#define OFF_WKT   131072u
#define OFF_WVT   262144u
#define OFF_WPT   393216u
#define OFF_W1T   524288u     // 512x256 packed bf16
#define OFF_W2T   786432u     // 256x512 packed bf16
#define OFF_QH    1048576u    // 24576 x 256 bf16
#define OFF_ATT   13631488u   // 4096 x 4 x 48 f32
#define OFF_OPART 16777216u   // 6 x 4096 x 256 f32

__device__ __forceinline__ unsigned short f2bf(float x) {
  union { float f; unsigned u; } v; v.f = x;
  unsigned r = v.u + 0x7FFFu + ((v.u >> 16) & 1u);
  return (unsigned short)(r >> 16);
}
__device__ __forceinline__ unsigned long long pack4bf(float a, float b, float c, float d) {
  unsigned d0 = (unsigned)f2bf(a) | ((unsigned)f2bf(b) << 16);
  unsigned d1 = (unsigned)f2bf(c) | ((unsigned)f2bf(d) << 16);
  return (unsigned long long)d0 | ((unsigned long long)d1 << 32);
}
// async global->LDS, 16B per lane; lds base must be wave-uniform
__device__ __forceinline__ void async_copy16(const float* g, float* l) {
  __builtin_amdgcn_global_load_lds(
      (const __attribute__((address_space(1))) unsigned int*)g,
      (__attribute__((address_space(3))) unsigned int*)l, 16, 0, 0);
}

// ===== prep: W[K][N] f32 -> MFMA-fragment-packed bf16 =====================
// layout: out[(ntile*KT + kt)*512 + lane*8 + j] = W[kt*32 + (lane>>4)*8 + j][ntile*16 + (lane&15)]
__global__ void __launch_bounds__(256)
prep_kernel(const float* __restrict__ wq, const float* __restrict__ wk,
            const float* __restrict__ wv, const float* __restrict__ wp,
            const float* __restrict__ w1, const float* __restrict__ w2,
            unsigned short* __restrict__ wsu16)
{
  const int blk = blockIdx.x, t = threadIdx.x;
  const float* src; unsigned short* dst; int N, KT, ntile;
  if (blk < 64) {
    int mi = blk >> 4; ntile = blk & 15; N = 256; KT = 8;
    src = (mi == 0) ? wq : (mi == 1) ? wk : (mi == 2) ? wv : wp;
    dst = wsu16 + (size_t)mi * 65536;
  } else if (blk < 96) {
    ntile = blk - 64; N = 512; KT = 8; src = w1; dst = wsu16 + OFF_W1T / 2;
  } else {
    ntile = blk - 96; N = 256; KT = 16; src = w2; dst = wsu16 + OFF_W2T / 2;
  }
  const int lane = t & 63;
  const int lr = lane & 15, quad = lane >> 4;
  const int ncol = ntile * 16 + lr;
  for (int kt = (t >> 6); kt < KT; kt += 4) {
    unsigned v8[8];
#pragma unroll
    for (int j = 0; j < 8; ++j) {
      int krow = kt * 32 + quad * 8 + j;
      v8[j] = f2bf(src[(size_t)krow * N + ncol]);
    }
    uint4 u;
    u.x = v8[0] | (v8[1] << 16); u.y = v8[2] | (v8[3] << 16);
    u.z = v8[4] | (v8[5] << 16); u.w = v8[6] | (v8[7] << 16);
    *(uint4*)(dst + ((size_t)(ntile * KT + kt) * 512 + lane * 8)) = u;
  }
}

// ===== proj-q: gather-transpose + LN + MFMA (64-px tiles) -> qh bf16 ======
__global__ void __launch_bounds__(256, 4)
projq_kernel(const float* __restrict__ src,
             const float* __restrict__ lng, const float* __restrict__ lnb,
             const unsigned short* __restrict__ wTp,
             const float* __restrict__ bias,
             unsigned short* __restrict__ qh)
{
  __shared__ __align__(16) unsigned short s_x[64 * 264];
  const int t = threadIdx.x, blk = blockIdx.x;
  const int n = blk >> 6, qp0 = (blk & 63) << 6;

  // stage + transpose raw as bf16
  {
    const int l16 = t & 15, dg = t >> 4;
    for (int it = 0; it < 16; ++it) {
      int dcol = it * 16 + dg;
      float4 x = *(const float4*)(src + ((size_t)(n * 256 + dcol)) * 4096 + qp0 + l16 * 4);
      s_x[(l16 * 4 + 0) * 264 + dcol] = f2bf(x.x);
      s_x[(l16 * 4 + 1) * 264 + dcol] = f2bf(x.y);
      s_x[(l16 * 4 + 2) * 264 + dcol] = f2bf(x.z);
      s_x[(l16 * 4 + 3) * 264 + dcol] = f2bf(x.w);
    }
  }
  __syncthreads();
  // two-pass LN (4 threads/row)
  {
    const int row = t >> 2, sl = t & 3;
    float s = 0.f, s2 = 0.f;
#pragma unroll
    for (int i = 0; i < 8; ++i) {
      bf16x8 xv = *(const bf16x8*)(s_x + row * 264 + (i * 4 + sl) * 8);
#pragma unroll
      for (int j = 0; j < 8; ++j) { float f = (float)xv[j]; s += f; s2 += f * f; }
    }
    s += __shfl_xor(s, 1, 64);  s += __shfl_xor(s, 2, 64);
    s2 += __shfl_xor(s2, 1, 64); s2 += __shfl_xor(s2, 2, 64);
    float mu = s * (1.f / 256.f);
    float var = s2 * (1.f / 256.f) - mu * mu;
    float istd = rsqrtf(var + EPSLN);
#pragma unroll
    for (int i = 0; i < 8; ++i) {
      int c = (i * 4 + sl) * 8;
      bf16x8 xv = *(const bf16x8*)(s_x + row * 264 + c);
      f32x4 ga = *(const f32x4*)(lng + c), gb = *(const f32x4*)(lng + c + 4);
      f32x4 ba = *(const f32x4*)(lnb + c), bb = *(const f32x4*)(lnb + c + 4);
      uint4 u;
      u.x = (unsigned)f2bf(((float)xv[0] - mu) * istd * ga[0] + ba[0]) |
            ((unsigned)f2bf(((float)xv[1] - mu) * istd * ga[1] + ba[1]) << 16);
      u.y = (unsigned)f2bf(((float)xv[2] - mu) * istd * ga[2] + ba[2]) |
            ((unsigned)f2bf(((float)xv[3] - mu) * istd * ga[3] + ba[3]) << 16);
      u.z = (unsigned)f2bf(((float)xv[4] - mu) * istd * gb[0] + bb[0]) |
            ((unsigned)f2bf(((float)xv[5] - mu) * istd * gb[1] + bb[1]) << 16);
      u.w = (unsigned)f2bf(((float)xv[6] - mu) * istd * gb[2] + bb[2]) |
            ((unsigned)f2bf(((float)xv[7] - mu) * istd * gb[3] + bb[3]) << 16);
      *(uint4*)(s_x + row * 264 + c) = u;
    }
  }
  __syncthreads();

  // MFMA: M=64, wave covers N-slice w*64
  const int w = t >> 6, lane = t & 63, lr = lane & 15, quad = lane >> 4;
  f32x4 acc[4][4];
  {
    f32x4 z = {0.f, 0.f, 0.f, 0.f};
#pragma unroll
    for (int a = 0; a < 4; ++a)
#pragma unroll
      for (int b = 0; b < 4; ++b) acc[a][b] = z;
  }
  for (int kt = 0; kt < 8; ++kt) {
    bf16x8 xf[4];
#pragma unroll
    for (int mt = 0; mt < 4; ++mt)
      xf[mt] = *(const bf16x8*)(s_x + (mt * 16 + lr) * 264 + kt * 32 + quad * 8);
#pragma unroll
    for (int nt = 0; nt < 4; ++nt) {
      bf16x8 wf = *(const bf16x8*)(wTp + ((size_t)((w * 4 + nt) * 8 + kt) * 512 + lane * 8));
#pragma unroll
      for (int mt = 0; mt < 4; ++mt)
        acc[nt][mt] = __builtin_amdgcn_mfma_f32_16x16x32_bf16(wf, xf[mt], acc[nt][mt], 0, 0, 0);
    }
  }
  __syncthreads();
#pragma unroll
  for (int nt = 0; nt < 4; ++nt) {
    int n0 = w * 64 + nt * 16 + quad * 4;
    f32x4 bb = *(const f32x4*)(bias + n0);
#pragma unroll
    for (int mt = 0; mt < 4; ++mt) {
      int m = mt * 16 + lr;
      f32x4 a = acc[nt][mt];
      *(unsigned long long*)(s_x + m * 264 + n0) =
          pack4bf(a[0] + bb[0], a[1] + bb[1], a[2] + bb[2], a[3] + bb[3]);
    }
  }
  __syncthreads();
  // dump 64 rows x 512B contiguous
  unsigned char* ob = (unsigned char*)qh + ((size_t)n * QL + qp0) * 512;
#pragma unroll
  for (int i = 0; i < 8; ++i) {
    int lin = i * 4096 + t * 16;
    int r = lin >> 9, off = lin & 511;
    *(uint4*)(ob + lin) = *(const uint4*)((const unsigned char*)s_x + r * 528 + off);
  }
}

// ===== fused proj k/v: async-LDS stage + 2-pass LN + MFMA + score/PV ======
__global__ void __launch_bounds__(256, 3)
projkv_kernel(const float* __restrict__ src,
              const float* __restrict__ lng, const float* __restrict__ lnb,
              const unsigned short* __restrict__ wTp,
              const float* __restrict__ bias,
              const unsigned short* __restrict__ qh,
              float* __restrict__ attg,
              float* __restrict__ opart,
              int kind)  // 0 = K (scores), 1 = V (PV partials)
{
  __shared__ __align__(16) float s_raw[32 * 272];
  __shared__ __align__(16) unsigned short s_x[32 * 264];
  const int t = threadIdx.x, blk = blockIdx.x;
  const int n = blk >> 10, qp0 = (blk & 1023) << 2;
  const int w = t >> 6, lane = t & 63;

  // async stage: wave w loads rows w*8 .. w*8+7 (1KB each) direct to LDS
  {
    const float* gb = src + (size_t)blk * 32 * 256 + lane * 4;
    float* lb = s_raw + (w * 8) * 272;
#pragma unroll
    for (int i = 0; i < 8; ++i)
      async_copy16(gb + (size_t)(w * 8 + i) * 256, lb + i * 272);
  }
  __syncthreads();

  // two-pass LN from LDS (8 threads/row)
  {
    const int row = t >> 3, sl = t & 7;
    float s = 0.f, s2 = 0.f;
#pragma unroll
    for (int i = 0; i < 8; ++i) {
      f32x4 x = *(const f32x4*)(s_raw + row * 272 + sl * 4 + i * 32);
      s  += x[0] + x[1] + x[2] + x[3];
      s2 += x[0] * x[0] + x[1] * x[1] + x[2] * x[2] + x[3] * x[3];
    }
    s += __shfl_xor(s, 1, 64);  s += __shfl_xor(s, 2, 64);  s += __shfl_xor(s, 4, 64);
    s2 += __shfl_xor(s2, 1, 64); s2 += __shfl_xor(s2, 2, 64); s2 += __shfl_xor(s2, 4, 64);
    float mu = s * (1.f / 256.f);
    float var = s2 * (1.f / 256.f) - mu * mu;
    float istd = rsqrtf(var + EPSLN);
#pragma unroll
    for (int i = 0; i < 8; ++i) {
      int c = sl * 4 + i * 32;
      f32x4 x = *(const f32x4*)(s_raw + row * 272 + c);
      f32x4 g = *(const f32x4*)(lng + c);
      f32x4 b = *(const f32x4*)(lnb + c);
      *(unsigned long long*)(s_x + row * 264 + c) =
          pack4bf((x[0] - mu) * istd * g[0] + b[0], (x[1] - mu) * istd * g[1] + b[1],
                  (x[2] - mu) * istd * g[2] + b[2], (x[3] - mu) * istd * g[3] + b[3]);
    }
  }
  __syncthreads();

  // MFMA: M=32, wave covers N-slice w*64
  const int lr = lane & 15, quad = lane >> 4;
  f32x4 acc[4][2];
  {
    f32x4 z = {0.f, 0.f, 0.f, 0.f};
#pragma unroll
    for (int a = 0; a < 4; ++a) { acc[a][0] = z; acc[a][1] = z; }
  }
  for (int kt = 0; kt < 8; ++kt) {
    bf16x8 xf[2];
    xf[0] = *(const bf16x8*)(s_x + lr * 264 + kt * 32 + quad * 8);
    xf[1] = *(const bf16x8*)(s_x + (16 + lr) * 264 + kt * 32 + quad * 8);
#pragma unroll
    for (int nt = 0; nt < 4; ++nt) {
      bf16x8 wf = *(const bf16x8*)(wTp + ((size_t)((w * 4 + nt) * 8 + kt) * 512 + lane * 8));
      acc[nt][0] = __builtin_amdgcn_mfma_f32_16x16x32_bf16(wf, xf[0], acc[nt][0], 0, 0, 0);
      acc[nt][1] = __builtin_amdgcn_mfma_f32_16x16x32_bf16(wf, xf[1], acc[nt][1], 0, 0, 0);
    }
  }
  __syncthreads();
#pragma unroll
  for (int nt = 0; nt < 4; ++nt) {
    int n0 = w * 64 + nt * 16 + quad * 4;
    f32x4 bb = *(const f32x4*)(bias + n0);
#pragma unroll
    for (int mt = 0; mt < 2; ++mt) {
      int m = mt * 16 + lr;
      f32x4 a = acc[nt][mt];
      *(unsigned long long*)(s_x + m * 264 + n0) =
          pack4bf(a[0] + bb[0], a[1] + bb[1], a[2] + bb[2], a[3] + bb[3]);
    }
  }
  __syncthreads();

  if (kind == 0) {
    if (t < 128) {
      const int p = t >> 5, m = (t >> 3) & 3, g = t & 7;
      const unsigned short* kr = s_x + (p * 8 + g) * 264 + m * 64;
      const unsigned short* qr = qh + ((size_t)n * QL + qp0 + p) * 256 + m * 64;
      float dot = 0.f;
#pragma unroll
      for (int i = 0; i < 8; ++i) {
        bf16x8 kv = *(const bf16x8*)(kr + i * 8);
        bf16x8 qv = *(const bf16x8*)(qr + i * 8);
#pragma unroll
        for (int j = 0; j < 8; ++j) dot += (float)kv[j] * (float)qv[j];
      }
      attg[(((size_t)(qp0 + p)) * 4 + m) * 48 + n * 8 + g] = dot * SCALE;
    }
  } else {
    const int p = t >> 6, c0 = (t & 63) * 4, m = c0 >> 6;
    const float* ar = attg + (((size_t)(qp0 + p)) * 4 + m) * 48 + n * 8;
    f32x4 a0 = *(const f32x4*)ar, a1 = *(const f32x4*)(ar + 4);
    float aw[8] = {a0[0], a0[1], a0[2], a0[3], a1[0], a1[1], a1[2], a1[3]};
    float o[4] = {0.f, 0.f, 0.f, 0.f};
#pragma unroll
    for (int g = 0; g < 8; ++g) {
      bf16x4 vv = *(const bf16x4*)(s_x + (p * 8 + g) * 264 + c0);
#pragma unroll
      for (int j = 0; j < 4; ++j) o[j] += aw[g] * (float)vv[j];
    }
    f32x4 ov = {o[0], o[1], o[2], o[3]};
    *(f32x4*)(opart + ((size_t)n * QL + qp0 + p) * 256 + c0) = ov;
  }
}

// ===== softmax + mask over 48 keys per (pixel, head) ======================
__global__ void __launch_bounds__(256)
softmax_kernel(float* __restrict__ attg, const int* __restrict__ mask)
{
  const int tg = blockIdx.x * 256 + threadIdx.x;   // 0..16383
  const int p = tg >> 2;
  float* row = attg + (size_t)tg * 48;
  float xs[48];
#pragma unroll
  for (int i = 0; i < 12; ++i) {
    float4 x = ((const float4*)row)[i];
    xs[4 * i] = x.x; xs[4 * i + 1] = x.y; xs[4 * i + 2] = x.z; xs[4 * i + 3] = x.w;
  }
#pragma unroll
  for (int n = 0; n < 6; ++n) {
    if (!mask[n * QL + p]) {
#pragma unroll
      for (int j = 0; j < 8; ++j) xs[n * 8 + j] = -1e9f;
    }
  }
  float mx = -3.0e38f;
#pragma unroll
  for (int i = 0; i < 48; ++i) mx = fmaxf(mx, xs[i]);
  float sm = 0.f;
#pragma unroll
  for (int i = 0; i < 48; ++i) { float e = __expf(xs[i] - mx); xs[i] = e; sm += e; }
  float inv = 1.f / sm;
#pragma unroll
  for (int i = 0; i < 12; ++i)
    ((float4*)row)[i] = make_float4(xs[4 * i] * inv, xs[4 * i + 1] * inv,
                                    xs[4 * i + 2] * inv, xs[4 * i + 3] * inv);
}

// ===== epilogue: MFMA proj + skip + LN + MLP + LN =========================
__global__ void __launch_bounds__(256)
epi_kernel(const float* __restrict__ opart, const float* __restrict__ skip,
           const unsigned short* __restrict__ wpp, const float* __restrict__ bp,
           const float* __restrict__ lng1, const float* __restrict__ lnb1,
           const unsigned short* __restrict__ w1p, const float* __restrict__ b1,
           const unsigned short* __restrict__ w2p, const float* __restrict__ b2,
           const float* __restrict__ lng2, const float* __restrict__ lnb2,
           float* __restrict__ out)
{
  __shared__ __align__(16) unsigned char smem[50688];
  unsigned short* s_a  = (unsigned short*)smem;            // 16*264 bf16
  float*          s_z  = (float*)(smem + 8448);            // 16*264 f32
  unsigned short* s_zb = (unsigned short*)(smem + 25344);  // 16*264 bf16
  unsigned short* s_h  = (unsigned short*)(smem + 33792);  // 16*528 bf16
  float*          s_z2 = (float*)(smem + 33792);           // alias over s_h
  const int t = threadIdx.x, q0 = blockIdx.x * 16;

  // a = sum_n opart[n], bf16-staged (float4 reads for MLP)
#pragma unroll
  for (int i = 0; i < 4; ++i) {
    int pos = i * 256 + t, p = pos >> 6, c4 = (pos & 63) * 4;
    const float* base = opart + (size_t)(q0 + p) * 256 + c4;
    f32x4 s = {0.f, 0.f, 0.f, 0.f};
#pragma unroll
    for (int nn = 0; nn < 6; ++nn) s += *(const f32x4*)(base + (size_t)nn * QL * 256);
    *(unsigned long long*)(s_a + p * 264 + c4) = pack4bf(s[0], s[1], s[2], s[3]);
  }
  __syncthreads();

  const int w = t >> 6, lane = t & 63, lr = lane & 15, quad = lane >> 4;

  // GEMM1: z = a @ wp + bp + skip
  {
    f32x4 acc[4];
    f32x4 z = {0.f, 0.f, 0.f, 0.f};
#pragma unroll
    for (int a = 0; a < 4; ++a) acc[a] = z;
    for (int kt = 0; kt < 8; ++kt) {
      bf16x8 xf = *(const bf16x8*)(s_a + lr * 264 + kt * 32 + quad * 8);
#pragma unroll
      for (int nt = 0; nt < 4; ++nt) {
        bf16x8 wf = *(const bf16x8*)(wpp + ((size_t)((w * 4 + nt) * 8 + kt) * 512 + lane * 8));
        acc[nt] = __builtin_amdgcn_mfma_f32_16x16x32_bf16(wf, xf, acc[nt], 0, 0, 0);
      }
    }
#pragma unroll
    for (int nt = 0; nt < 4; ++nt) {
      int n0 = w * 64 + nt * 16 + quad * 4;
      f32x4 bb = *(const f32x4*)(bp + n0);
      f32x4 sk;
#pragma unroll
      for (int j = 0; j < 4; ++j) sk[j] = skip[(size_t)(n0 + j) * QL + q0 + lr];
      *(f32x4*)(s_z + lr * 264 + n0) = acc[nt] + bb + sk;
    }
  }
  __syncthreads();

  // LN1
  {
    int r = t >> 4, l = t & 15;
    float s = 0.f, s2 = 0.f;
#pragma unroll
    for (int i = 0; i < 16; ++i) {
      float x = s_z[r * 264 + l + 16 * i];
      s += x; s2 += x * x;
    }
    s += __shfl_xor(s, 1, 64); s += __shfl_xor(s, 2, 64);
    s += __shfl_xor(s, 4, 64); s += __shfl_xor(s, 8, 64);
    s2 += __shfl_xor(s2, 1, 64); s2 += __shfl_xor(s2, 2, 64);
    s2 += __shfl_xor(s2, 4, 64); s2 += __shfl_xor(s2, 8, 64);
    float mu = s * (1.f / 256.f);
    float var = s2 * (1.f / 256.f) - mu * mu;
    float istd = rsqrtf(var + EPSLN);
#pragma unroll
    for (int i = 0; i < 16; ++i) {
      int d = l + 16 * i;
      float nv = (s_z[r * 264 + d] - mu) * istd * lng1[d] + lnb1[d];
      s_z[r * 264 + d] = nv;
      s_zb[r * 264 + d] = f2bf(nv);
    }
  }
  __syncthreads();

  // GEMM2: h = gelu(z @ w1 + b1), N=512
  {
    f32x4 acc[8];
    f32x4 z = {0.f, 0.f, 0.f, 0.f};
#pragma unroll
    for (int a = 0; a < 8; ++a) acc[a] = z;
    for (int kt = 0; kt < 8; ++kt) {
      bf16x8 xf = *(const bf16x8*)(s_zb + lr * 264 + kt * 32 + quad * 8);
#pragma unroll
      for (int nt = 0; nt < 8; ++nt) {
        bf16x8 wf = *(const bf16x8*)(w1p + ((size_t)((w * 8 + nt) * 8 + kt) * 512 + lane * 8));
        acc[nt] = __builtin_amdgcn_mfma_f32_16x16x32_bf16(wf, xf, acc[nt], 0, 0, 0);
      }
    }
#pragma unroll
    for (int nt = 0; nt < 8; ++nt) {
      int n0 = w * 128 + nt * 16 + quad * 4;
      f32x4 bb = *(const f32x4*)(b1 + n0);
      float hv[4];
#pragma unroll
      for (int j = 0; j < 4; ++j) {
        float val = acc[nt][j] + bb[j];
        hv[j] = 0.5f * val * (1.f + erff(val * 0.70710678118654752f));
      }
      *(unsigned long long*)(s_h + lr * 528 + n0) = pack4bf(hv[0], hv[1], hv[2], hv[3]);
    }
  }
  __syncthreads();

  // GEMM3: z2 = z + h @ w2 + b2 (K=512), result overlays s_h region
  {
    f32x4 acc[4];
    f32x4 z = {0.f, 0.f, 0.f, 0.f};
#pragma unroll
    for (int a = 0; a < 4; ++a) acc[a] = z;
    for (int kt = 0; kt < 16; ++kt) {
      bf16x8 xf = *(const bf16x8*)(s_h + lr * 528 + kt * 32 + quad * 8);
#pragma unroll
      for (int nt = 0; nt < 4; ++nt) {
        bf16x8 wf = *(const bf16x8*)(w2p + ((size_t)((w * 4 + nt) * 16 + kt) * 512 + lane * 8));
        acc[nt] = __builtin_amdgcn_mfma_f32_16x16x32_bf16(wf, xf, acc[nt], 0, 0, 0);
      }
    }
    f32x4 res[4];
#pragma unroll
    for (int nt = 0; nt < 4; ++nt) {
      int n0 = w * 64 + nt * 16 + quad * 4;
      f32x4 bb = *(const f32x4*)(b2 + n0);
      f32x4 zr = *(const f32x4*)(s_z + lr * 264 + n0);
      res[nt] = acc[nt] + bb + zr;
    }
    __syncthreads();   // all s_h reads done before overlay write
#pragma unroll
    for (int nt = 0; nt < 4; ++nt) {
      int n0 = w * 64 + nt * 16 + quad * 4;
      *(f32x4*)(s_z2 + lr * 264 + n0) = res[nt];
    }
  }
  __syncthreads();

  // LN2 in place
  {
    int r = t >> 4, l = t & 15;
    float s = 0.f, s2 = 0.f;
#pragma unroll
    for (int i = 0; i < 16; ++i) {
      float x = s_z2[r * 264 + l + 16 * i];
      s += x; s2 += x * x;
    }
    s += __shfl_xor(s, 1, 64); s += __shfl_xor(s, 2, 64);
    s += __shfl_xor(s, 4, 64); s += __shfl_xor(s, 8, 64);
    s2 += __shfl_xor(s2, 1, 64); s2 += __shfl_xor(s2, 2, 64);
    s2 += __shfl_xor(s2, 4, 64); s2 += __shfl_xor(s2, 8, 64);
    float mu = s * (1.f / 256.f);
    float var = s2 * (1.f / 256.f) - mu * mu;
    float istd = rsqrtf(var + EPSLN);
#pragma unroll
    for (int i = 0; i < 16; ++i) {
      int d = l + 16 * i;
      s_z2[r * 264 + d] = (s_z2[r * 264 + d] - mu) * istd * lng2[d] + lnb2[d];
    }
  }
  __syncthreads();

  // transposed store
#pragma unroll
  for (int i = 0; i < 16; ++i) {
    int c = i * 16 + (t >> 4), p = t & 15;
    out[(size_t)c * QL + q0 + p] = s_z2[p * 264 + c];
  }
}

extern "C" void kernel_launch(void* const* d_in, const int* in_sizes, int n_in,
                              void* d_out, int out_size, void* d_ws, size_t ws_size,
                              hipStream_t stream) {
  (void)in_sizes; (void)n_in; (void)out_size; (void)ws_size;
  const float* q     = (const float*)d_in[0];
  const float* k     = (const float*)d_in[1];
  const float* v     = (const float*)d_in[2];
  const float* skip  = (const float*)d_in[3];
  const int*   mask  = (const int*)d_in[4];
  const float* lnqg  = (const float*)d_in[5];
  const float* lnqb  = (const float*)d_in[6];
  const float* wq    = (const float*)d_in[7];
  const float* bq    = (const float*)d_in[8];
  const float* lnkg  = (const float*)d_in[9];
  const float* lnkb  = (const float*)d_in[10];
  const float* wk    = (const float*)d_in[11];
  const float* bk    = (const float*)d_in[12];
  const float* lnvg  = (const float*)d_in[13];
  const float* lnvb  = (const float*)d_in[14];
  const float* wv    = (const float*)d_in[15];
  const float* bv    = (const float*)d_in[16];
  const float* wp    = (const float*)d_in[17];
  const float* bp    = (const float*)d_in[18];
  const float* lng1  = (const float*)d_in[19];
  const float* lnb1  = (const float*)d_in[20];
  const float* w1    = (const float*)d_in[21];
  const float* b1    = (const float*)d_in[22];
  const float* w2    = (const float*)d_in[23];
  const float* b2    = (const float*)d_in[24];
  const float* lng2  = (const float*)d_in[25];
  const float* lnb2  = (const float*)d_in[26];
  float* out = (float*)d_out;

  unsigned char* ws = (unsigned char*)d_ws;
  unsigned short* wsu16 = (unsigned short*)d_ws;
  unsigned short* wqT = (unsigned short*)(ws + OFF_WQT);
  unsigned short* wkT = (unsigned short*)(ws + OFF_WKT);
  unsigned short* wvT = (unsigned short*)(ws + OFF_WVT);
  unsigned short* wpT = (unsigned short*)(ws + OFF_WPT);
  unsigned short* w1T = (unsigned short*)(ws + OFF_W1T);
  unsigned short* w2T = (unsigned short*)(ws + OFF_W2T);
  unsigned short* qh  = (unsigned short*)(ws + OFF_QH);
  float* attg  = (float*)(ws + OFF_ATT);
  float* opart = (float*)(ws + OFF_OPART);

  hipLaunchKernelGGL(prep_kernel, dim3(112), dim3(256), 0, stream,
                     wq, wk, wv, wp, w1, w2, wsu16);
  hipLaunchKernelGGL(projq_kernel, dim3(384), dim3(256), 0, stream,
                     q, lnqg, lnqb, wqT, bq, qh);
  hipLaunchKernelGGL(projkv_kernel, dim3(6144), dim3(256), 0, stream,
                     k, lnkg, lnkb, wkT, bk, qh, attg, opart, 0);
  hipLaunchKernelGGL(softmax_kernel, dim3(64), dim3(256), 0, stream,
                     attg, mask);
  hipLaunchKernelGGL(projkv_kernel, dim3(6144), dim3(256), 0, stream,
                     v, lnvg, lnvb, wvT, bv, qh, attg, opart, 1);
  hipLaunchKernelGGL(epi_kernel, dim3(QL / 16), dim3(256), 0, stream,
                     opart, skip, wpT, bp, lng1, lnb1, w1T, b1, w2T, b2, lng2, lnb2, out);
}